// Round 8
// baseline (232.264 us; speedup 1.0000x reference)
//
#include <hip/hip_runtime.h>
#include <hip/hip_fp16.h>

#define N_NODES 50000
#define E_EDGES 800000
#define ET (E_EDGES + N_NODES)

typedef _Float16 h8 __attribute__((ext_vector_type(8)));
typedef float f32x16 __attribute__((ext_vector_type(16)));
typedef int i32x4 __attribute__((ext_vector_type(4)));

__device__ __forceinline__ float lrelu(float v) { return v > 0.f ? v : 0.2f * v; }

// ---------- prep: degree histogram (8 shards) + W1/W2 fp16 + Aw rows ----------
__global__ __launch_bounds__(256) void prep_kernel(const int* __restrict__ ei,
                                                   const float* __restrict__ W1,
                                                   const float* __restrict__ W2,
                                                   const float* __restrict__ as1,
                                                   const float* __restrict__ ad1,
                                                   _Float16* __restrict__ w1h,
                                                   _Float16* __restrict__ w2h,
                                                   int* __restrict__ deg8) {
    int i = blockIdx.x * 256 + threadIdx.x;
    if (i < E_EDGES) {
        int d = __builtin_nontemporal_load(ei + E_EDGES + i);
        atomicAdd(&deg8[(threadIdx.x & 7) * N_NODES + d], 1);
    } else if (i < E_EDGES + 4096) {
        int j = (i - E_EDGES) * 8;
#pragma unroll
        for (int t = 0; t < 8; t++) w1h[j + t] = (_Float16)W1[j + t];
    } else if (i < E_EDGES + 4608) {
        int j = (i - (E_EDGES + 4096)) * 8;
#pragma unroll
        for (int t = 0; t < 8; t++) w2h[j + t] = (_Float16)W2[j + t];
    } else if (i < E_EDGES + 5376) {
        int j = (i - (E_EDGES + 4608)) * 8;
#pragma unroll
        for (int t = 0; t < 8; t++) w1h[136 * 256 + j + t] = (_Float16)0.f;
    } else if (i < E_EDGES + 7424) {
        // Aw: rows 128..135 = attention-combined weights
        int a = i - (E_EDGES + 5376);  // 0..2047
        int h = a >> 8, k = a & 255;
        const float* av = (h < 4 ? as1 : ad1) + (h & 3) * 32;
        const float* wb = W1 + (size_t)(h & 3) * 32 * 256 + k;
        float s = 0.f;
#pragma unroll
        for (int c = 0; c < 32; c++) s += av[c] * wb[(size_t)c * 256];
        w1h[(size_t)(128 + h) * 256 + k] = (_Float16)s;
    }
}

// ---------- GEMM1 (MFMA): h1h[N,128] = cvt(x) @ w1h[0:128]^T ; cols 128..135 -> asc1/adc1 ----------
__global__ __launch_bounds__(256) void gemm1_mfma(const float* __restrict__ x,
                                                  const _Float16* __restrict__ w1h,
                                                  _Float16* __restrict__ h1h,
                                                  float* __restrict__ asc1,
                                                  float* __restrict__ adc1) {
    int wid = threadIdx.x >> 6, lane = threadIdx.x & 63;
    int rbase = blockIdx.x * 128 + wid * 32;
    if (rbase >= N_NODES) return;
    int l31 = lane & 31, l5 = lane >> 5;
    int ar = rbase + l31;
    if (ar > N_NODES - 1) ar = N_NODES - 1;
    const float* ap = x + (size_t)ar * 256 + l5 * 8;
    const _Float16* bp = w1h + (size_t)l31 * 256 + l5 * 8;
    f32x16 acc0 = {}, acc1 = {}, acc2 = {}, acc3 = {}, acc4 = {};
#pragma unroll 4
    for (int ks = 0; ks < 16; ks++) {
        float4 xa = *(const float4*)(ap + ks * 16);
        float4 xb = *(const float4*)(ap + ks * 16 + 4);
        h8 av;
        av[0] = (_Float16)xa.x; av[1] = (_Float16)xa.y;
        av[2] = (_Float16)xa.z; av[3] = (_Float16)xa.w;
        av[4] = (_Float16)xb.x; av[5] = (_Float16)xb.y;
        av[6] = (_Float16)xb.z; av[7] = (_Float16)xb.w;
        h8 b0 = *(const h8*)(bp + ks * 16);
        h8 b1 = *(const h8*)(bp + 32 * 256 + ks * 16);
        h8 b2 = *(const h8*)(bp + 64 * 256 + ks * 16);
        h8 b3 = *(const h8*)(bp + 96 * 256 + ks * 16);
        h8 b4 = *(const h8*)(bp + 128 * 256 + ks * 16);
        acc0 = __builtin_amdgcn_mfma_f32_32x32x16_f16(av, b0, acc0, 0, 0, 0);
        acc1 = __builtin_amdgcn_mfma_f32_32x32x16_f16(av, b1, acc1, 0, 0, 0);
        acc2 = __builtin_amdgcn_mfma_f32_32x32x16_f16(av, b2, acc2, 0, 0, 0);
        acc3 = __builtin_amdgcn_mfma_f32_32x32x16_f16(av, b3, acc3, 0, 0, 0);
        acc4 = __builtin_amdgcn_mfma_f32_32x32x16_f16(av, b4, acc4, 0, 0, 0);
    }
#pragma unroll
    for (int j = 0; j < 16; j++) {
        int row = rbase + (j & 3) + 8 * (j >> 2) + 4 * l5;
        if (row < N_NODES) {
            h1h[(size_t)row * 128 + 0  + l31] = (_Float16)acc0[j];
            h1h[(size_t)row * 128 + 32 + l31] = (_Float16)acc1[j];
            h1h[(size_t)row * 128 + 64 + l31] = (_Float16)acc2[j];
            h1h[(size_t)row * 128 + 96 + l31] = (_Float16)acc3[j];
            float v4 = acc4[j];
            if (l31 < 4) asc1[(size_t)row * 4 + l31] = v4;
            else if (l31 < 8) adc1[(size_t)row * 4 + (l31 - 4)] = v4;
        }
    }
}

// ---------- device-wide scan of (deg+1), 2 stages ----------
__global__ __launch_bounds__(1024) void scanA_kernel(const int* __restrict__ deg8,
                                                     int* __restrict__ off,
                                                     int* __restrict__ bsum) {
    __shared__ int s[1024];
    int t = threadIdx.x;
    int n = blockIdx.x * 1024 + t;
    int v = 0;
    if (n < N_NODES) {
        v = 1;
#pragma unroll
        for (int sh = 0; sh < 8; sh++) v += deg8[sh * N_NODES + n];
    }
    s[t] = v;
    __syncthreads();
    for (int d = 1; d < 1024; d <<= 1) {
        int u = (t >= d) ? s[t - d] : 0;
        __syncthreads();
        s[t] += u;
        __syncthreads();
    }
    if (n < N_NODES) off[n] = s[t] - v;
    if (t == 1023) bsum[blockIdx.x] = s[1023];
}

// scanC: integrate bsum prefix (1 wave) + add base, emit off/cursor
__global__ __launch_bounds__(1024) void scanC_kernel(const int* __restrict__ bsum,
                                                     int* __restrict__ off,
                                                     int* __restrict__ cursor) {
    __shared__ int sb[64];
    int t = threadIdx.x;
    if (t < 64) {
        int v = (t < 49) ? bsum[t] : 0;
#pragma unroll
        for (int d = 1; d < 64; d <<= 1) {
            int u = __shfl_up(v, d);
            if (t >= d) v += u;
        }
        sb[t] = v;  // inclusive
    }
    __syncthreads();
    int b = blockIdx.x;
    int base = (b == 0) ? 0 : sb[b - 1];
    int n = b * 1024 + t;
    if (n < N_NODES) {
        int o = off[n] + base;
        off[n] = o;
        cursor[n] = o;
    }
    if (n == 0) off[N_NODES] = ET;
}

// ---------- fill CSR: one 16B AoS record per edge {src, half4 p1, 0} (nt store) ----------
__global__ void fill_kernel(const int* __restrict__ ei, int* __restrict__ cursor,
                            const float* __restrict__ asc1, const float* __restrict__ adc1,
                            int4* __restrict__ combo) {
    int i = blockIdx.x * blockDim.x + threadIdx.x;
    if (i >= ET) return;
    int s, d;
    if (i < E_EDGES) {
        s = __builtin_nontemporal_load(ei + i);
        d = __builtin_nontemporal_load(ei + E_EDGES + i);
    } else {
        s = i - E_EDGES; d = s;
    }
    int pos = atomicAdd(&cursor[d], 1);
    float4 av = *(const float4*)(asc1 + (size_t)s * 4);
    float4 dv = *(const float4*)(adc1 + (size_t)d * 4);
    __half2 p01 = __floats2half2_rn(__expf(lrelu(av.x + dv.x)), __expf(lrelu(av.y + dv.y)));
    __half2 p23 = __floats2half2_rn(__expf(lrelu(av.z + dv.z)), __expf(lrelu(av.w + dv.w)));
    i32x4 rec;
    rec[0] = s;
    rec[1] = *(int*)&p01;
    rec[2] = *(int*)&p23;
    rec[3] = 0;
    __builtin_nontemporal_store(rec, (i32x4*)&combo[pos]);
}

// ---------- Layer-1 aggregation: 2 waves per node, edges split by parity, full-width gathers ----------
__global__ __launch_bounds__(256) void agg1_kernel(const __half* __restrict__ h1h,
                                                   const int4* __restrict__ combo,
                                                   const float* __restrict__ b1,
                                                   const int* __restrict__ off,
                                                   __half* __restrict__ h1b) {
    __shared__ float4 sb[2][64];
    int wid = threadIdx.x >> 6, lane = threadIdx.x & 63;
    int nodeLocal = wid >> 1;          // 0..1
    int k = wid & 1;                   // edge parity handled by this wave
    int node = blockIdx.x * 2 + nodeLocal;   // N even, grid exact
    int hh = lane >> 4;
    const __half2* h1h2 = (const __half2*)h1h;
    int s0 = off[node], s1 = off[node + 1];
    float den = 0.f, a0 = 0.f, a1 = 0.f;
    int j = s0 + k;
    for (; j + 7 <= s1; j += 8) {      // edges j, j+2, j+4, j+6
        i32x4 c[4];
#pragma unroll
        for (int u = 0; u < 4; u++)
            c[u] = __builtin_nontemporal_load((const i32x4*)&combo[j + 2 * u]);
        __half2 hv[4];
#pragma unroll
        for (int u = 0; u < 4; u++) hv[u] = h1h2[(size_t)c[u][0] * 64 + lane];
#pragma unroll
        for (int u = 0; u < 4; u++) {
            union { int u32; __half2 h; } v;
            v.u32 = (hh & 2) ? c[u][2] : c[u][1];
            float p = __half2float((hh & 1) ? v.h.y : v.h.x);
            float2 f = __half22float2(hv[u]);
            den += p;
            a0 += p * f.x;
            a1 += p * f.y;
        }
    }
    for (; j < s1; j += 2) {
        i32x4 c = __builtin_nontemporal_load((const i32x4*)&combo[j]);
        union { int u32; __half2 h; } v;
        v.u32 = (hh & 2) ? c[2] : c[1];
        float p = __half2float((hh & 1) ? v.h.y : v.h.x);
        float2 f = __half22float2(h1h2[(size_t)c[0] * 64 + lane]);
        den += p;
        a0 += p * f.x;
        a1 += p * f.y;
    }
    if (k == 0) sb[nodeLocal][lane] = make_float4(a0, a1, den, 0.f);
    __syncthreads();
    if (k == 1) {
        float4 o = sb[nodeLocal][lane];
        a0 += o.x; a1 += o.y; den += o.z;
        float inv = 1.f / (den + 1e-16f);
        float o0 = fmaxf(a0 * inv + b1[2 * lane], 0.f);
        float o1 = fmaxf(a1 * inv + b1[2 * lane + 1], 0.f);
        ((__half2*)h1b)[(size_t)node * 64 + lane] = __floats2half2_rn(o0, o1);
    }
}

// ---------- GEMM2 (MFMA): h2h[N,32] = h1b @ w2h^T ; epilogue asc2/adc2 ----------
__global__ __launch_bounds__(256) void gemm2_mfma(const __half* __restrict__ h1b,
                                                  const _Float16* __restrict__ w2h,
                                                  const float* __restrict__ as2,
                                                  const float* __restrict__ ad2,
                                                  __half* __restrict__ h2h,
                                                  float* __restrict__ asc2,
                                                  float* __restrict__ adc2) {
    int wid = threadIdx.x >> 6, lane = threadIdx.x & 63;
    int rbase = blockIdx.x * 128 + wid * 32;
    if (rbase >= N_NODES) return;
    int l31 = lane & 31, l5 = lane >> 5;
    int ar = rbase + l31;
    if (ar > N_NODES - 1) ar = N_NODES - 1;
    const _Float16* ap = (const _Float16*)h1b + (size_t)ar * 128 + l5 * 8;
    const _Float16* bp = w2h + (size_t)l31 * 128 + l5 * 8;
    f32x16 acc = {};
#pragma unroll
    for (int ks = 0; ks < 8; ks++) {
        h8 av = *(const h8*)(ap + ks * 16);
        h8 bv = *(const h8*)(bp + ks * 16);
        acc = __builtin_amdgcn_mfma_f32_32x32x16_f16(av, bv, acc, 0, 0, 0);
    }
    float asw = as2[l31], adw = ad2[l31];
#pragma unroll
    for (int j = 0; j < 16; j++) {
        int row = rbase + (j & 3) + 8 * (j >> 2) + 4 * l5;
        float v = acc[j];
        float sv = v * asw, dv = v * adw;
#pragma unroll
        for (int m = 1; m <= 16; m <<= 1) {
            sv += __shfl_xor(sv, m);
            dv += __shfl_xor(dv, m);
        }
        if (row < N_NODES) {
            h2h[(size_t)row * 32 + l31] = __float2half(v);
            if (l31 == 0) { asc2[row] = sv; adc2[row] = dv; }
        }
    }
}

// ---------- Layer-2 aggregation + log_softmax (p2 on the fly, 4 gathers in flight) ----------
__global__ __launch_bounds__(256) void agg2_kernel(const __half* __restrict__ h2h,
                                                   const int4* __restrict__ combo,
                                                   const float* __restrict__ asc2,
                                                   const float* __restrict__ adc2,
                                                   const float* __restrict__ b2,
                                                   const int* __restrict__ off,
                                                   float* __restrict__ out) {
    int wid = threadIdx.x >> 6, lane = threadIdx.x & 63;
    int node = blockIdx.x * 4 + wid;
    if (node >= N_NODES) return;
    int g = lane >> 4;
    int li = lane & 15;
    const __half2* h2h2 = (const __half2*)h2h;
    float adv = adc2[node];
    int s0 = off[node], s1 = off[node + 1];
    float den = 0.f, a0 = 0.f, a1 = 0.f;
    int j = s0 + g;
    for (; j + 16 <= s1; j += 16) {
        int s[4];
#pragma unroll
        for (int u = 0; u < 4; u++) s[u] = __builtin_nontemporal_load(&combo[j + 4 * u].x);
        float av[4];
#pragma unroll
        for (int u = 0; u < 4; u++) av[u] = asc2[s[u]];
        __half2 hv[4];
#pragma unroll
        for (int u = 0; u < 4; u++) hv[u] = h2h2[(size_t)s[u] * 16 + li];
#pragma unroll
        for (int u = 0; u < 4; u++) {
            float p = __expf(lrelu(av[u] + adv));
            float2 f = __half22float2(hv[u]);
            den += p;
            a0 += p * f.x;
            a1 += p * f.y;
        }
    }
    for (; j < s1; j += 4) {
        int s = __builtin_nontemporal_load(&combo[j].x);
        float p = __expf(lrelu(asc2[s] + adv));
        float2 f = __half22float2(h2h2[(size_t)s * 16 + li]);
        den += p;
        a0 += p * f.x;
        a1 += p * f.y;
    }
    den += __shfl_xor(den, 16); den += __shfl_xor(den, 32);
    a0 += __shfl_xor(a0, 16);  a0 += __shfl_xor(a0, 32);
    a1 += __shfl_xor(a1, 16);  a1 += __shfl_xor(a1, 32);
    float inv = 1.f / (den + 1e-16f);
    float v0 = a0 * inv + b2[2 * li];
    float v1 = a1 * inv + b2[2 * li + 1];
    float mx = fmaxf(v0, v1);
#pragma unroll
    for (int msk = 8; msk >= 1; msk >>= 1) mx = fmaxf(mx, __shfl_xor(mx, msk));
    float se = __expf(v0 - mx) + __expf(v1 - mx);
#pragma unroll
    for (int msk = 8; msk >= 1; msk >>= 1) se += __shfl_xor(se, msk);
    float lse = mx + __logf(se);
    if (lane < 16) {
        ((float2*)out)[(size_t)node * 16 + li] = make_float2(v0 - lse, v1 - lse);
    }
}

extern "C" void kernel_launch(void* const* d_in, const int* in_sizes, int n_in,
                              void* d_out, int out_size, void* d_ws, size_t ws_size,
                              hipStream_t stream) {
    const float* x   = (const float*)d_in[0];
    const int* ei    = (const int*)d_in[1];
    const float* W1  = (const float*)d_in[2];
    const float* as1 = (const float*)d_in[3];
    const float* ad1 = (const float*)d_in[4];
    const float* b1  = (const float*)d_in[5];
    const float* W2  = (const float*)d_in[6];
    const float* as2 = (const float*)d_in[7];
    const float* ad2 = (const float*)d_in[8];
    const float* b2  = (const float*)d_in[9];
    float* out = (float*)d_out;

    char* base = (char*)d_ws;
    int4* combo   = (int4*)base;                       // ET*16 = 13,600,000
    _Float16* w1h = (_Float16*)(base + 25600000);      // 81,920
    _Float16* w2h = (_Float16*)(base + 25681920);      // 8,192
    _Float16* h1h = (_Float16*)(base + 25690112);      // 12,800,000
    __half* h1b   = (__half*)(base + 38490112);        // 12,800,000
    __half* h2h   = (__half*)(base + 51290112);        //  3,200,000
    float* asc1   = (float*)(base + 54490112);         //    800,000
    float* adc1   = (float*)(base + 55290112);         //    800,000
    float* asc2   = (float*)(base + 56090112);         //    200,000
    float* adc2   = (float*)(base + 56290112);         //    200,000
    int* deg8     = (int*)(base + 56490112);           //  1,600,000 (8 shards)
    int* off      = (int*)(base + 58090112);           //    200,004
    int* cursor   = (int*)(base + 58290116);           //    200,004
    int* bsum     = (int*)(base + 58490120);           //        256

    hipMemsetAsync(deg8, 0, 8 * N_NODES * sizeof(int), stream);

    prep_kernel<<<(E_EDGES + 7424 + 255) / 256, 256, 0, stream>>>(ei, W1, W2, as1, ad1, w1h, w2h, deg8);
    gemm1_mfma<<<391, 256, 0, stream>>>(x, w1h, h1h, asc1, adc1);
    scanA_kernel<<<49, 1024, 0, stream>>>(deg8, off, bsum);
    scanC_kernel<<<49, 1024, 0, stream>>>(bsum, off, cursor);
    fill_kernel<<<(ET + 255) / 256, 256, 0, stream>>>(ei, cursor, asc1, adc1, combo);
    agg1_kernel<<<N_NODES / 2, 256, 0, stream>>>((const __half*)h1h, combo, b1, off, h1b);
    gemm2_mfma<<<391, 256, 0, stream>>>(h1b, w2h, as2, ad2, h2h, asc2, adc2);
    agg2_kernel<<<(N_NODES + 3) / 4, 256, 0, stream>>>(h2h, combo, asc2, adc2, b2, off, out);
}

// Round 9
// 202.406 us; speedup vs baseline: 1.1475x; 1.1475x over previous
//
#include <hip/hip_runtime.h>
#include <hip/hip_fp16.h>

#define N_NODES 50000
#define E_EDGES 800000
#define ET (E_EDGES + N_NODES)

typedef _Float16 h8 __attribute__((ext_vector_type(8)));
typedef float f32x16 __attribute__((ext_vector_type(16)));

__device__ __forceinline__ float lrelu(float v) { return v > 0.f ? v : 0.2f * v; }

// ---------- prep: W1/W2 fp16 conversion + Aw rows (tiny, 29 blocks) ----------
__global__ __launch_bounds__(256) void prep_kernel(const float* __restrict__ W1,
                                                   const float* __restrict__ W2,
                                                   const float* __restrict__ as1,
                                                   const float* __restrict__ ad1,
                                                   _Float16* __restrict__ w1h,
                                                   _Float16* __restrict__ w2h) {
    int i = blockIdx.x * 256 + threadIdx.x;
    if (i < 4096) {
        int j = i * 8;
#pragma unroll
        for (int t = 0; t < 8; t++) w1h[j + t] = (_Float16)W1[j + t];
    } else if (i < 4608) {
        int j = (i - 4096) * 8;
#pragma unroll
        for (int t = 0; t < 8; t++) w2h[j + t] = (_Float16)W2[j + t];
    } else if (i < 5376) {
        int j = (i - 4608) * 8;
#pragma unroll
        for (int t = 0; t < 8; t++) w1h[136 * 256 + j + t] = (_Float16)0.f;
    } else if (i < 7424) {
        // Aw: rows 128..135 = attention-combined weights
        int a = i - 5376;  // 0..2047
        int h = a >> 8, k = a & 255;
        const float* av = (h < 4 ? as1 : ad1) + (h & 3) * 32;
        const float* wb = W1 + (size_t)(h & 3) * 32 * 256 + k;
        float s = 0.f;
#pragma unroll
        for (int c = 0; c < 32; c++) s += av[c] * wb[(size_t)c * 256];
        w1h[(size_t)(128 + h) * 256 + k] = (_Float16)s;
    }
}

// ---------- GEMM1 (MFMA) + fused degree histogram ----------
__global__ __launch_bounds__(256) void gemm1_mfma(const float* __restrict__ x,
                                                  const int* __restrict__ ei,
                                                  const _Float16* __restrict__ w1h,
                                                  _Float16* __restrict__ h1h,
                                                  float* __restrict__ asc1,
                                                  float* __restrict__ adc1,
                                                  int* __restrict__ deg8) {
    // fused histogram: 8 dst edges per thread (100k threads cover 800k edges)
    int tid = blockIdx.x * 256 + threadIdx.x;
    if (tid * 8 < E_EDGES) {
        const int4* d4 = (const int4*)(ei + E_EDGES);
        int4 a = d4[tid * 2], b = d4[tid * 2 + 1];
        int sh = (threadIdx.x & 7) * N_NODES;
        atomicAdd(&deg8[sh + a.x], 1);
        atomicAdd(&deg8[sh + a.y], 1);
        atomicAdd(&deg8[sh + a.z], 1);
        atomicAdd(&deg8[sh + a.w], 1);
        atomicAdd(&deg8[sh + b.x], 1);
        atomicAdd(&deg8[sh + b.y], 1);
        atomicAdd(&deg8[sh + b.z], 1);
        atomicAdd(&deg8[sh + b.w], 1);
    }

    int wid = threadIdx.x >> 6, lane = threadIdx.x & 63;
    int rbase = blockIdx.x * 128 + wid * 32;
    if (rbase >= N_NODES) return;
    int l31 = lane & 31, l5 = lane >> 5;
    int ar = rbase + l31;
    if (ar > N_NODES - 1) ar = N_NODES - 1;
    const float* ap = x + (size_t)ar * 256 + l5 * 8;
    const _Float16* bp = w1h + (size_t)l31 * 256 + l5 * 8;
    f32x16 acc0 = {}, acc1 = {}, acc2 = {}, acc3 = {}, acc4 = {};
#pragma unroll 4
    for (int ks = 0; ks < 16; ks++) {
        float4 xa = *(const float4*)(ap + ks * 16);
        float4 xb = *(const float4*)(ap + ks * 16 + 4);
        h8 av;
        av[0] = (_Float16)xa.x; av[1] = (_Float16)xa.y;
        av[2] = (_Float16)xa.z; av[3] = (_Float16)xa.w;
        av[4] = (_Float16)xb.x; av[5] = (_Float16)xb.y;
        av[6] = (_Float16)xb.z; av[7] = (_Float16)xb.w;
        h8 b0 = *(const h8*)(bp + ks * 16);
        h8 b1 = *(const h8*)(bp + 32 * 256 + ks * 16);
        h8 b2 = *(const h8*)(bp + 64 * 256 + ks * 16);
        h8 b3 = *(const h8*)(bp + 96 * 256 + ks * 16);
        h8 b4 = *(const h8*)(bp + 128 * 256 + ks * 16);
        acc0 = __builtin_amdgcn_mfma_f32_32x32x16_f16(av, b0, acc0, 0, 0, 0);
        acc1 = __builtin_amdgcn_mfma_f32_32x32x16_f16(av, b1, acc1, 0, 0, 0);
        acc2 = __builtin_amdgcn_mfma_f32_32x32x16_f16(av, b2, acc2, 0, 0, 0);
        acc3 = __builtin_amdgcn_mfma_f32_32x32x16_f16(av, b3, acc3, 0, 0, 0);
        acc4 = __builtin_amdgcn_mfma_f32_32x32x16_f16(av, b4, acc4, 0, 0, 0);
    }
#pragma unroll
    for (int j = 0; j < 16; j++) {
        int row = rbase + (j & 3) + 8 * (j >> 2) + 4 * l5;
        if (row < N_NODES) {
            h1h[(size_t)row * 128 + 0  + l31] = (_Float16)acc0[j];
            h1h[(size_t)row * 128 + 32 + l31] = (_Float16)acc1[j];
            h1h[(size_t)row * 128 + 64 + l31] = (_Float16)acc2[j];
            h1h[(size_t)row * 128 + 96 + l31] = (_Float16)acc3[j];
            float v4 = acc4[j];
            if (l31 < 4) asc1[(size_t)row * 4 + l31] = v4;
            else if (l31 < 8) adc1[(size_t)row * 4 + (l31 - 4)] = v4;
        }
    }
}

// ---------- device-wide scan of (deg+1), 2 stages ----------
__global__ __launch_bounds__(1024) void scanA_kernel(const int* __restrict__ deg8,
                                                     int* __restrict__ off,
                                                     int* __restrict__ bsum) {
    __shared__ int s[1024];
    int t = threadIdx.x;
    int n = blockIdx.x * 1024 + t;
    int v = 0;
    if (n < N_NODES) {
        v = 1;
#pragma unroll
        for (int sh = 0; sh < 8; sh++) v += deg8[sh * N_NODES + n];
    }
    s[t] = v;
    __syncthreads();
    for (int d = 1; d < 1024; d <<= 1) {
        int u = (t >= d) ? s[t - d] : 0;
        __syncthreads();
        s[t] += u;
        __syncthreads();
    }
    if (n < N_NODES) off[n] = s[t] - v;
    if (t == 1023) bsum[blockIdx.x] = s[1023];
}

__global__ __launch_bounds__(1024) void scanC_kernel(const int* __restrict__ bsum,
                                                     int* __restrict__ off,
                                                     int* __restrict__ cursor) {
    __shared__ int sb[64];
    int t = threadIdx.x;
    if (t < 64) {
        int v = (t < 49) ? bsum[t] : 0;
#pragma unroll
        for (int d = 1; d < 64; d <<= 1) {
            int u = __shfl_up(v, d);
            if (t >= d) v += u;
        }
        sb[t] = v;  // inclusive
    }
    __syncthreads();
    int b = blockIdx.x;
    int base = (b == 0) ? 0 : sb[b - 1];
    int n = b * 1024 + t;
    if (n < N_NODES) {
        int o = off[n] + base;
        off[n] = o;
        cursor[n] = o;
    }
    if (n == 0) off[N_NODES] = ET;
}

// ---------- fill CSR: one 16B AoS record per edge {src, half4 p1, 0} ----------
__global__ void fill_kernel(const int* __restrict__ ei, int* __restrict__ cursor,
                            const float* __restrict__ asc1, const float* __restrict__ adc1,
                            int4* __restrict__ combo) {
    int i = blockIdx.x * blockDim.x + threadIdx.x;
    if (i >= ET) return;
    int s, d;
    if (i < E_EDGES) { s = ei[i]; d = ei[E_EDGES + i]; }
    else { s = i - E_EDGES; d = s; }
    int pos = atomicAdd(&cursor[d], 1);
    float4 av = *(const float4*)(asc1 + (size_t)s * 4);
    float4 dv = *(const float4*)(adc1 + (size_t)d * 4);
    __half2 p01 = __floats2half2_rn(__expf(lrelu(av.x + dv.x)), __expf(lrelu(av.y + dv.y)));
    __half2 p23 = __floats2half2_rn(__expf(lrelu(av.z + dv.z)), __expf(lrelu(av.w + dv.w)));
    int4 rec;
    rec.x = s;
    rec.y = *(int*)&p01;
    rec.z = *(int*)&p23;
    rec.w = 0;
    combo[pos] = rec;
}

// ---------- Layer-1 aggregation: wave per node, 16 gathers in flight ----------
__global__ __launch_bounds__(256) void agg1_kernel(const __half* __restrict__ h1h,
                                                   const int4* __restrict__ combo,
                                                   const float* __restrict__ b1,
                                                   const int* __restrict__ off,
                                                   __half* __restrict__ h1b) {
    int wid = threadIdx.x >> 6, lane = threadIdx.x & 63;
    int node = blockIdx.x * 4 + wid;
    if (node >= N_NODES) return;
    int hh = lane >> 4;
    const __half2* h1h2 = (const __half2*)h1h;
    int s0 = off[node], s1 = off[node + 1];
    float den = 0.f, a0 = 0.f, a1 = 0.f;
    int j = s0;
    for (; j + 16 <= s1; j += 16) {
        int src[16];
        float p[16];
#pragma unroll
        for (int u = 0; u < 16; u++) {
            int4 c = combo[j + u];
            src[u] = c.x;
            union { int u32; __half2 h; } v;
            v.u32 = (hh & 2) ? c.z : c.y;
            p[u] = __half2float((hh & 1) ? v.h.y : v.h.x);
        }
        __half2 hv[16];
#pragma unroll
        for (int u = 0; u < 16; u++) hv[u] = h1h2[(size_t)src[u] * 64 + lane];
#pragma unroll
        for (int u = 0; u < 16; u++) {
            float2 f = __half22float2(hv[u]);
            den += p[u];
            a0 += p[u] * f.x;
            a1 += p[u] * f.y;
        }
    }
    for (; j + 4 <= s1; j += 4) {
        int src[4];
        float p[4];
#pragma unroll
        for (int u = 0; u < 4; u++) {
            int4 c = combo[j + u];
            src[u] = c.x;
            union { int u32; __half2 h; } v;
            v.u32 = (hh & 2) ? c.z : c.y;
            p[u] = __half2float((hh & 1) ? v.h.y : v.h.x);
        }
        __half2 hv[4];
#pragma unroll
        for (int u = 0; u < 4; u++) hv[u] = h1h2[(size_t)src[u] * 64 + lane];
#pragma unroll
        for (int u = 0; u < 4; u++) {
            float2 f = __half22float2(hv[u]);
            den += p[u];
            a0 += p[u] * f.x;
            a1 += p[u] * f.y;
        }
    }
    for (; j < s1; j++) {
        int4 c = combo[j];
        union { int u32; __half2 h; } v;
        v.u32 = (hh & 2) ? c.z : c.y;
        float p = __half2float((hh & 1) ? v.h.y : v.h.x);
        float2 f = __half22float2(h1h2[(size_t)c.x * 64 + lane]);
        den += p;
        a0 += p * f.x;
        a1 += p * f.y;
    }
    float inv = 1.f / (den + 1e-16f);
    float o0 = fmaxf(a0 * inv + b1[2 * lane], 0.f);
    float o1 = fmaxf(a1 * inv + b1[2 * lane + 1], 0.f);
    ((__half2*)h1b)[(size_t)node * 64 + lane] = __floats2half2_rn(o0, o1);
}

// ---------- GEMM2 (MFMA): h2h[N,32] = h1b @ w2h^T ; epilogue asc2/adc2 ----------
__global__ __launch_bounds__(256) void gemm2_mfma(const __half* __restrict__ h1b,
                                                  const _Float16* __restrict__ w2h,
                                                  const float* __restrict__ as2,
                                                  const float* __restrict__ ad2,
                                                  __half* __restrict__ h2h,
                                                  float* __restrict__ asc2,
                                                  float* __restrict__ adc2) {
    int wid = threadIdx.x >> 6, lane = threadIdx.x & 63;
    int rbase = blockIdx.x * 128 + wid * 32;
    if (rbase >= N_NODES) return;
    int l31 = lane & 31, l5 = lane >> 5;
    int ar = rbase + l31;
    if (ar > N_NODES - 1) ar = N_NODES - 1;
    const _Float16* ap = (const _Float16*)h1b + (size_t)ar * 128 + l5 * 8;
    const _Float16* bp = w2h + (size_t)l31 * 128 + l5 * 8;
    f32x16 acc = {};
#pragma unroll
    for (int ks = 0; ks < 8; ks++) {
        h8 av = *(const h8*)(ap + ks * 16);
        h8 bv = *(const h8*)(bp + ks * 16);
        acc = __builtin_amdgcn_mfma_f32_32x32x16_f16(av, bv, acc, 0, 0, 0);
    }
    float asw = as2[l31], adw = ad2[l31];
#pragma unroll
    for (int j = 0; j < 16; j++) {
        int row = rbase + (j & 3) + 8 * (j >> 2) + 4 * l5;
        float v = acc[j];
        float sv = v * asw, dv = v * adw;
#pragma unroll
        for (int m = 1; m <= 16; m <<= 1) {
            sv += __shfl_xor(sv, m);
            dv += __shfl_xor(dv, m);
        }
        if (row < N_NODES) {
            h2h[(size_t)row * 32 + l31] = __float2half(v);
            if (l31 == 0) { asc2[row] = sv; adc2[row] = dv; }
        }
    }
}

// ---------- Layer-2 aggregation + log_softmax (p2 on the fly) ----------
__global__ __launch_bounds__(256) void agg2_kernel(const __half* __restrict__ h2h,
                                                   const int4* __restrict__ combo,
                                                   const float* __restrict__ asc2,
                                                   const float* __restrict__ adc2,
                                                   const float* __restrict__ b2,
                                                   const int* __restrict__ off,
                                                   float* __restrict__ out) {
    int wid = threadIdx.x >> 6, lane = threadIdx.x & 63;
    int node = blockIdx.x * 4 + wid;
    if (node >= N_NODES) return;
    int g = lane >> 4;
    int li = lane & 15;
    const __half2* h2h2 = (const __half2*)h2h;
    float adv = adc2[node];
    int s0 = off[node], s1 = off[node + 1];
    float den = 0.f, a0 = 0.f, a1 = 0.f;
    int j = s0 + g;
    for (; j + 16 <= s1; j += 16) {
        int s[4];
#pragma unroll
        for (int u = 0; u < 4; u++) s[u] = combo[j + 4 * u].x;
        float av[4];
#pragma unroll
        for (int u = 0; u < 4; u++) av[u] = asc2[s[u]];
        __half2 hv[4];
#pragma unroll
        for (int u = 0; u < 4; u++) hv[u] = h2h2[(size_t)s[u] * 16 + li];
#pragma unroll
        for (int u = 0; u < 4; u++) {
            float p = __expf(lrelu(av[u] + adv));
            float2 f = __half22float2(hv[u]);
            den += p;
            a0 += p * f.x;
            a1 += p * f.y;
        }
    }
    for (; j < s1; j += 4) {
        int s = combo[j].x;
        float p = __expf(lrelu(asc2[s] + adv));
        float2 f = __half22float2(h2h2[(size_t)s * 16 + li]);
        den += p;
        a0 += p * f.x;
        a1 += p * f.y;
    }
    den += __shfl_xor(den, 16); den += __shfl_xor(den, 32);
    a0 += __shfl_xor(a0, 16);  a0 += __shfl_xor(a0, 32);
    a1 += __shfl_xor(a1, 16);  a1 += __shfl_xor(a1, 32);
    float inv = 1.f / (den + 1e-16f);
    float v0 = a0 * inv + b2[2 * li];
    float v1 = a1 * inv + b2[2 * li + 1];
    float mx = fmaxf(v0, v1);
#pragma unroll
    for (int msk = 8; msk >= 1; msk >>= 1) mx = fmaxf(mx, __shfl_xor(mx, msk));
    float se = __expf(v0 - mx) + __expf(v1 - mx);
#pragma unroll
    for (int msk = 8; msk >= 1; msk >>= 1) se += __shfl_xor(se, msk);
    float lse = mx + __logf(se);
    if (lane < 16) {
        ((float2*)out)[(size_t)node * 16 + li] = make_float2(v0 - lse, v1 - lse);
    }
}

extern "C" void kernel_launch(void* const* d_in, const int* in_sizes, int n_in,
                              void* d_out, int out_size, void* d_ws, size_t ws_size,
                              hipStream_t stream) {
    const float* x   = (const float*)d_in[0];
    const int* ei    = (const int*)d_in[1];
    const float* W1  = (const float*)d_in[2];
    const float* as1 = (const float*)d_in[3];
    const float* ad1 = (const float*)d_in[4];
    const float* b1  = (const float*)d_in[5];
    const float* W2  = (const float*)d_in[6];
    const float* as2 = (const float*)d_in[7];
    const float* ad2 = (const float*)d_in[8];
    const float* b2  = (const float*)d_in[9];
    float* out = (float*)d_out;

    char* base = (char*)d_ws;
    int4* combo   = (int4*)base;                       // ET*16 = 13,600,000
    _Float16* w1h = (_Float16*)(base + 25600000);      // 81,920
    _Float16* w2h = (_Float16*)(base + 25681920);      // 8,192
    _Float16* h1h = (_Float16*)(base + 25690112);      // 12,800,000
    __half* h1b   = (__half*)(base + 38490112);        // 12,800,000
    __half* h2h   = (__half*)(base + 51290112);        //  3,200,000
    float* asc1   = (float*)(base + 54490112);         //    800,000
    float* adc1   = (float*)(base + 55290112);         //    800,000
    float* asc2   = (float*)(base + 56090112);         //    200,000
    float* adc2   = (float*)(base + 56290112);         //    200,000
    int* deg8     = (int*)(base + 56490112);           //  1,600,000 (8 shards)
    int* off      = (int*)(base + 58090112);           //    200,004
    int* cursor   = (int*)(base + 58290116);           //    200,004
    int* bsum     = (int*)(base + 58490120);           //        256

    hipMemsetAsync(deg8, 0, 8 * N_NODES * sizeof(int), stream);

    prep_kernel<<<29, 256, 0, stream>>>(W1, W2, as1, ad1, w1h, w2h);
    gemm1_mfma<<<391, 256, 0, stream>>>(x, ei, w1h, h1h, asc1, adc1, deg8);
    scanA_kernel<<<49, 1024, 0, stream>>>(deg8, off, bsum);
    scanC_kernel<<<49, 1024, 0, stream>>>(bsum, off, cursor);
    fill_kernel<<<(ET + 255) / 256, 256, 0, stream>>>(ei, cursor, asc1, adc1, combo);
    agg1_kernel<<<(N_NODES + 3) / 4, 256, 0, stream>>>((const __half*)h1h, combo, b1, off, h1b);
    gemm2_mfma<<<391, 256, 0, stream>>>(h1b, w2h, as2, ad2, h2h, asc2, adc2);
    agg2_kernel<<<(N_NODES + 3) / 4, 256, 0, stream>>>(h2h, combo, asc2, adc2, b2, off, out);
}

// Round 10
// 166.712 us; speedup vs baseline: 1.3932x; 1.2141x over previous
//
#include <hip/hip_runtime.h>
#include <hip/hip_fp16.h>

#define N_NODES 50000
#define E_EDGES 800000
#define ET (E_EDGES + N_NODES)
#define NBKT 1024          // padded bucket count (782 used)
#define BCAP 2048          // scratch capacity per bucket
#define K1_BLOCKS 256
#define K1_EPB 3328        // 256*3328 = 851,968 >= ET

typedef _Float16 h8 __attribute__((ext_vector_type(8)));
typedef float f32x16 __attribute__((ext_vector_type(16)));

__device__ __forceinline__ float lrelu(float v) { return v > 0.f ? v : 0.2f * v; }

// ---------- prep: W1/W2 fp16 conversion + Aw rows ----------
__global__ __launch_bounds__(256) void prep_kernel(const float* __restrict__ W1,
                                                   const float* __restrict__ W2,
                                                   const float* __restrict__ as1,
                                                   const float* __restrict__ ad1,
                                                   _Float16* __restrict__ w1h,
                                                   _Float16* __restrict__ w2h) {
    int i = blockIdx.x * 256 + threadIdx.x;
    if (i < 4096) {
        int j = i * 8;
#pragma unroll
        for (int t = 0; t < 8; t++) w1h[j + t] = (_Float16)W1[j + t];
    } else if (i < 4608) {
        int j = (i - 4096) * 8;
#pragma unroll
        for (int t = 0; t < 8; t++) w2h[j + t] = (_Float16)W2[j + t];
    } else if (i < 5376) {
        int j = (i - 4608) * 8;
#pragma unroll
        for (int t = 0; t < 8; t++) w1h[136 * 256 + j + t] = (_Float16)0.f;
    } else if (i < 7424) {
        int a = i - 5376;  // 0..2047
        int h = a >> 8, k = a & 255;
        const float* av = (h < 4 ? as1 : ad1) + (h & 3) * 32;
        const float* wb = W1 + (size_t)(h & 3) * 32 * 256 + k;
        float s = 0.f;
#pragma unroll
        for (int c = 0; c < 32; c++) s += av[c] * wb[(size_t)c * 256];
        w1h[(size_t)(128 + h) * 256 + k] = (_Float16)s;
    }
}

// ---------- GEMM1 (MFMA): h1h[N,128] = cvt(x) @ w1h[0:128]^T ; cols 128..135 -> asc1/adc1 ----------
__global__ __launch_bounds__(256) void gemm1_mfma(const float* __restrict__ x,
                                                  const _Float16* __restrict__ w1h,
                                                  _Float16* __restrict__ h1h,
                                                  float* __restrict__ asc1,
                                                  float* __restrict__ adc1) {
    int wid = threadIdx.x >> 6, lane = threadIdx.x & 63;
    int rbase = blockIdx.x * 128 + wid * 32;
    if (rbase >= N_NODES) return;
    int l31 = lane & 31, l5 = lane >> 5;
    int ar = rbase + l31;
    if (ar > N_NODES - 1) ar = N_NODES - 1;
    const float* ap = x + (size_t)ar * 256 + l5 * 8;
    const _Float16* bp = w1h + (size_t)l31 * 256 + l5 * 8;
    f32x16 acc0 = {}, acc1 = {}, acc2 = {}, acc3 = {}, acc4 = {};
#pragma unroll 4
    for (int ks = 0; ks < 16; ks++) {
        float4 xa = *(const float4*)(ap + ks * 16);
        float4 xb = *(const float4*)(ap + ks * 16 + 4);
        h8 av;
        av[0] = (_Float16)xa.x; av[1] = (_Float16)xa.y;
        av[2] = (_Float16)xa.z; av[3] = (_Float16)xa.w;
        av[4] = (_Float16)xb.x; av[5] = (_Float16)xb.y;
        av[6] = (_Float16)xb.z; av[7] = (_Float16)xb.w;
        h8 b0 = *(const h8*)(bp + ks * 16);
        h8 b1 = *(const h8*)(bp + 32 * 256 + ks * 16);
        h8 b2 = *(const h8*)(bp + 64 * 256 + ks * 16);
        h8 b3 = *(const h8*)(bp + 96 * 256 + ks * 16);
        h8 b4 = *(const h8*)(bp + 128 * 256 + ks * 16);
        acc0 = __builtin_amdgcn_mfma_f32_32x32x16_f16(av, b0, acc0, 0, 0, 0);
        acc1 = __builtin_amdgcn_mfma_f32_32x32x16_f16(av, b1, acc1, 0, 0, 0);
        acc2 = __builtin_amdgcn_mfma_f32_32x32x16_f16(av, b2, acc2, 0, 0, 0);
        acc3 = __builtin_amdgcn_mfma_f32_32x32x16_f16(av, b3, acc3, 0, 0, 0);
        acc4 = __builtin_amdgcn_mfma_f32_32x32x16_f16(av, b4, acc4, 0, 0, 0);
    }
#pragma unroll
    for (int j = 0; j < 16; j++) {
        int row = rbase + (j & 3) + 8 * (j >> 2) + 4 * l5;
        if (row < N_NODES) {
            h1h[(size_t)row * 128 + 0  + l31] = (_Float16)acc0[j];
            h1h[(size_t)row * 128 + 32 + l31] = (_Float16)acc1[j];
            h1h[(size_t)row * 128 + 64 + l31] = (_Float16)acc2[j];
            h1h[(size_t)row * 128 + 96 + l31] = (_Float16)acc3[j];
            float v4 = acc4[j];
            if (l31 < 4) asc1[(size_t)row * 4 + l31] = v4;
            else if (l31 < 8) adc1[(size_t)row * 4 + (l31 - 4)] = v4;
        }
    }
}

// ---------- K1: coarse partition by dst>>6 into bucketed scratch (LDS hist + 1 reserve atomic per block-bucket) ----------
__global__ __launch_bounds__(256) void part_kernel(const int* __restrict__ ei,
                                                   int* __restrict__ cursor,
                                                   int2* __restrict__ scratch) {
    __shared__ int hcnt[NBKT];
    __shared__ int hbase[NBKT];
    int tid = threadIdx.x;
#pragma unroll
    for (int u = 0; u < NBKT / 256; u++) hcnt[u * 256 + tid] = 0;
    __syncthreads();
    int e0 = blockIdx.x * K1_EPB;
    // pass A: count dst buckets
    for (int k = tid; k < K1_EPB; k += 256) {
        int i = e0 + k;
        if (i >= ET) break;
        int d = (i < E_EDGES) ? ei[E_EDGES + i] : (i - E_EDGES);
        atomicAdd(&hcnt[d >> 6], 1);
    }
    __syncthreads();
    // reserve ranges
#pragma unroll
    for (int u = 0; u < NBKT / 256; u++) {
        int b = u * 256 + tid;
        int c = hcnt[b];
        hbase[b] = (c > 0) ? atomicAdd(&cursor[b], c) : 0;
        hcnt[b] = 0;  // reuse as local cursor
    }
    __syncthreads();
    // pass B: scatter {src,dst}
    for (int k = tid; k < K1_EPB; k += 256) {
        int i = e0 + k;
        if (i >= ET) break;
        int s, d;
        if (i < E_EDGES) { s = ei[i]; d = ei[E_EDGES + i]; }
        else { s = i - E_EDGES; d = s; }
        int b = d >> 6;
        int pos = hbase[b] + atomicAdd(&hcnt[b], 1);
        scratch[(size_t)b * BCAP + pos] = make_int2(s, d);
    }
}

// ---------- K2: scan bucket totals -> bucketStart; off[N] = ET ----------
__global__ __launch_bounds__(1024) void bscan_kernel(const int* __restrict__ cursor,
                                                     int* __restrict__ bucketStart,
                                                     int* __restrict__ off) {
    __shared__ int s[NBKT];
    int t = threadIdx.x;
    int v = cursor[t];
    s[t] = v;
    __syncthreads();
    for (int d = 1; d < NBKT; d <<= 1) {
        int u = (t >= d) ? s[t - d] : 0;
        __syncthreads();
        s[t] += u;
        __syncthreads();
    }
    bucketStart[t] = s[t] - v;  // exclusive
    if (t == NBKT - 1) off[N_NODES] = s[t];
}

// ---------- K3: fine sort within bucket (64 nodes), write off + combo records ----------
__global__ __launch_bounds__(256) void fine_kernel(const int2* __restrict__ scratch,
                                                   const int* __restrict__ cursor,
                                                   const int* __restrict__ bucketStart,
                                                   const float* __restrict__ asc1,
                                                   const float* __restrict__ adc1,
                                                   int* __restrict__ off,
                                                   int4* __restrict__ combo) {
    __shared__ int2 rec[BCAP];
    __shared__ int fh[64];
    __shared__ int fcur[64];
    int b = blockIdx.x;
    int tid = threadIdx.x;
    int cnt = cursor[b];
    int gbase = bucketStart[b];
    if (tid < 64) fh[tid] = 0;
    __syncthreads();
    for (int k = tid; k < cnt; k += 256) {
        int2 r = scratch[(size_t)b * BCAP + k];
        rec[k] = r;
        atomicAdd(&fh[r.y & 63], 1);
    }
    __syncthreads();
    if (tid < 64) {
        int v = fh[tid];
        int incl = v;
#pragma unroll
        for (int d = 1; d < 64; d <<= 1) {
            int u = __shfl_up(incl, d);
            if (tid >= d) incl += u;
        }
        int excl = incl - v;
        fcur[tid] = excl;
        int n = b * 64 + tid;
        if (n < N_NODES) off[n] = gbase + excl;
    }
    __syncthreads();
    for (int k = tid; k < cnt; k += 256) {
        int2 r = rec[k];
        int pos = gbase + atomicAdd(&fcur[r.y & 63], 1);
        float4 av = *(const float4*)(asc1 + (size_t)r.x * 4);
        float4 dv = *(const float4*)(adc1 + (size_t)r.y * 4);
        __half2 p01 = __floats2half2_rn(__expf(lrelu(av.x + dv.x)), __expf(lrelu(av.y + dv.y)));
        __half2 p23 = __floats2half2_rn(__expf(lrelu(av.z + dv.z)), __expf(lrelu(av.w + dv.w)));
        int4 o;
        o.x = r.x;
        o.y = *(int*)&p01;
        o.z = *(int*)&p23;
        o.w = 0;
        combo[pos] = o;
    }
}

// ---------- Layer-1 aggregation: wave per node, 16 gathers in flight ----------
__global__ __launch_bounds__(256) void agg1_kernel(const __half* __restrict__ h1h,
                                                   const int4* __restrict__ combo,
                                                   const float* __restrict__ b1,
                                                   const int* __restrict__ off,
                                                   __half* __restrict__ h1b) {
    int wid = threadIdx.x >> 6, lane = threadIdx.x & 63;
    int node = blockIdx.x * 4 + wid;
    if (node >= N_NODES) return;
    int hh = lane >> 4;
    const __half2* h1h2 = (const __half2*)h1h;
    int s0 = off[node], s1 = off[node + 1];
    float den = 0.f, a0 = 0.f, a1 = 0.f;
    int j = s0;
    for (; j + 16 <= s1; j += 16) {
        int src[16];
        float p[16];
#pragma unroll
        for (int u = 0; u < 16; u++) {
            int4 c = combo[j + u];
            src[u] = c.x;
            union { int u32; __half2 h; } v;
            v.u32 = (hh & 2) ? c.z : c.y;
            p[u] = __half2float((hh & 1) ? v.h.y : v.h.x);
        }
        __half2 hv[16];
#pragma unroll
        for (int u = 0; u < 16; u++) hv[u] = h1h2[(size_t)src[u] * 64 + lane];
#pragma unroll
        for (int u = 0; u < 16; u++) {
            float2 f = __half22float2(hv[u]);
            den += p[u];
            a0 += p[u] * f.x;
            a1 += p[u] * f.y;
        }
    }
    for (; j + 4 <= s1; j += 4) {
        int src[4];
        float p[4];
#pragma unroll
        for (int u = 0; u < 4; u++) {
            int4 c = combo[j + u];
            src[u] = c.x;
            union { int u32; __half2 h; } v;
            v.u32 = (hh & 2) ? c.z : c.y;
            p[u] = __half2float((hh & 1) ? v.h.y : v.h.x);
        }
        __half2 hv[4];
#pragma unroll
        for (int u = 0; u < 4; u++) hv[u] = h1h2[(size_t)src[u] * 64 + lane];
#pragma unroll
        for (int u = 0; u < 4; u++) {
            float2 f = __half22float2(hv[u]);
            den += p[u];
            a0 += p[u] * f.x;
            a1 += p[u] * f.y;
        }
    }
    for (; j < s1; j++) {
        int4 c = combo[j];
        union { int u32; __half2 h; } v;
        v.u32 = (hh & 2) ? c.z : c.y;
        float p = __half2float((hh & 1) ? v.h.y : v.h.x);
        float2 f = __half22float2(h1h2[(size_t)c.x * 64 + lane]);
        den += p;
        a0 += p * f.x;
        a1 += p * f.y;
    }
    float inv = 1.f / (den + 1e-16f);
    float o0 = fmaxf(a0 * inv + b1[2 * lane], 0.f);
    float o1 = fmaxf(a1 * inv + b1[2 * lane + 1], 0.f);
    ((__half2*)h1b)[(size_t)node * 64 + lane] = __floats2half2_rn(o0, o1);
}

// ---------- GEMM2 (MFMA): h2h[N,32] = h1b @ w2h^T ; epilogue asc2/adc2 ----------
__global__ __launch_bounds__(256) void gemm2_mfma(const __half* __restrict__ h1b,
                                                  const _Float16* __restrict__ w2h,
                                                  const float* __restrict__ as2,
                                                  const float* __restrict__ ad2,
                                                  __half* __restrict__ h2h,
                                                  float* __restrict__ asc2,
                                                  float* __restrict__ adc2) {
    int wid = threadIdx.x >> 6, lane = threadIdx.x & 63;
    int rbase = blockIdx.x * 128 + wid * 32;
    if (rbase >= N_NODES) return;
    int l31 = lane & 31, l5 = lane >> 5;
    int ar = rbase + l31;
    if (ar > N_NODES - 1) ar = N_NODES - 1;
    const _Float16* ap = (const _Float16*)h1b + (size_t)ar * 128 + l5 * 8;
    const _Float16* bp = w2h + (size_t)l31 * 128 + l5 * 8;
    f32x16 acc = {};
#pragma unroll
    for (int ks = 0; ks < 8; ks++) {
        h8 av = *(const h8*)(ap + ks * 16);
        h8 bv = *(const h8*)(bp + ks * 16);
        acc = __builtin_amdgcn_mfma_f32_32x32x16_f16(av, bv, acc, 0, 0, 0);
    }
    float asw = as2[l31], adw = ad2[l31];
#pragma unroll
    for (int j = 0; j < 16; j++) {
        int row = rbase + (j & 3) + 8 * (j >> 2) + 4 * l5;
        float v = acc[j];
        float sv = v * asw, dv = v * adw;
#pragma unroll
        for (int m = 1; m <= 16; m <<= 1) {
            sv += __shfl_xor(sv, m);
            dv += __shfl_xor(dv, m);
        }
        if (row < N_NODES) {
            h2h[(size_t)row * 32 + l31] = __float2half(v);
            if (l31 == 0) { asc2[row] = sv; adc2[row] = dv; }
        }
    }
}

// ---------- Layer-2 aggregation + log_softmax (p2 on the fly) ----------
__global__ __launch_bounds__(256) void agg2_kernel(const __half* __restrict__ h2h,
                                                   const int4* __restrict__ combo,
                                                   const float* __restrict__ asc2,
                                                   const float* __restrict__ adc2,
                                                   const float* __restrict__ b2,
                                                   const int* __restrict__ off,
                                                   float* __restrict__ out) {
    int wid = threadIdx.x >> 6, lane = threadIdx.x & 63;
    int node = blockIdx.x * 4 + wid;
    if (node >= N_NODES) return;
    int g = lane >> 4;
    int li = lane & 15;
    const __half2* h2h2 = (const __half2*)h2h;
    float adv = adc2[node];
    int s0 = off[node], s1 = off[node + 1];
    float den = 0.f, a0 = 0.f, a1 = 0.f;
    int j = s0 + g;
    for (; j + 16 <= s1; j += 16) {
        int s[4];
#pragma unroll
        for (int u = 0; u < 4; u++) s[u] = combo[j + 4 * u].x;
        float av[4];
#pragma unroll
        for (int u = 0; u < 4; u++) av[u] = asc2[s[u]];
        __half2 hv[4];
#pragma unroll
        for (int u = 0; u < 4; u++) hv[u] = h2h2[(size_t)s[u] * 16 + li];
#pragma unroll
        for (int u = 0; u < 4; u++) {
            float p = __expf(lrelu(av[u] + adv));
            float2 f = __half22float2(hv[u]);
            den += p;
            a0 += p * f.x;
            a1 += p * f.y;
        }
    }
    for (; j < s1; j += 4) {
        int s = combo[j].x;
        float p = __expf(lrelu(asc2[s] + adv));
        float2 f = __half22float2(h2h2[(size_t)s * 16 + li]);
        den += p;
        a0 += p * f.x;
        a1 += p * f.y;
    }
    den += __shfl_xor(den, 16); den += __shfl_xor(den, 32);
    a0 += __shfl_xor(a0, 16);  a0 += __shfl_xor(a0, 32);
    a1 += __shfl_xor(a1, 16);  a1 += __shfl_xor(a1, 32);
    float inv = 1.f / (den + 1e-16f);
    float v0 = a0 * inv + b2[2 * li];
    float v1 = a1 * inv + b2[2 * li + 1];
    float mx = fmaxf(v0, v1);
#pragma unroll
    for (int msk = 8; msk >= 1; msk >>= 1) mx = fmaxf(mx, __shfl_xor(mx, msk));
    float se = __expf(v0 - mx) + __expf(v1 - mx);
#pragma unroll
    for (int msk = 8; msk >= 1; msk >>= 1) se += __shfl_xor(se, msk);
    float lse = mx + __logf(se);
    if (lane < 16) {
        ((float2*)out)[(size_t)node * 16 + li] = make_float2(v0 - lse, v1 - lse);
    }
}

extern "C" void kernel_launch(void* const* d_in, const int* in_sizes, int n_in,
                              void* d_out, int out_size, void* d_ws, size_t ws_size,
                              hipStream_t stream) {
    const float* x   = (const float*)d_in[0];
    const int* ei    = (const int*)d_in[1];
    const float* W1  = (const float*)d_in[2];
    const float* as1 = (const float*)d_in[3];
    const float* ad1 = (const float*)d_in[4];
    const float* b1  = (const float*)d_in[5];
    const float* W2  = (const float*)d_in[6];
    const float* as2 = (const float*)d_in[7];
    const float* ad2 = (const float*)d_in[8];
    const float* b2  = (const float*)d_in[9];
    float* out = (float*)d_out;

    char* base = (char*)d_ws;
    int4* combo   = (int4*)base;                        // 13,600,000
    int2* scratch = (int2*)(base + 13600000);           // 1024*2048*8 = 16,777,216
    _Float16* w1h = (_Float16*)(base + 30377216);       // 81,920
    _Float16* w2h = (_Float16*)(base + 30459136);       // 8,192
    _Float16* h1h = (_Float16*)(base + 30467328);       // 12,800,000
    __half* h1b   = (__half*)(base + 43267328);         // 12,800,000
    __half* h2h   = (__half*)(base + 56067328);         //  3,200,000
    float* asc1   = (float*)(base + 59267328);          //    800,000
    float* adc1   = (float*)(base + 60067328);          //    800,000
    float* asc2   = (float*)(base + 60867328);          //    200,000
    float* adc2   = (float*)(base + 61067328);          //    200,000
    int* off      = (int*)(base + 61267328);            //    200,004
    int* cursor   = (int*)(base + 61467332);            //      4,096
    int* bstart   = (int*)(base + 61471428);            //      4,096

    hipMemsetAsync(cursor, 0, NBKT * sizeof(int), stream);

    prep_kernel<<<29, 256, 0, stream>>>(W1, W2, as1, ad1, w1h, w2h);
    part_kernel<<<K1_BLOCKS, 256, 0, stream>>>(ei, cursor, scratch);
    bscan_kernel<<<1, 1024, 0, stream>>>(cursor, bstart, off);
    gemm1_mfma<<<391, 256, 0, stream>>>(x, w1h, h1h, asc1, adc1);
    fine_kernel<<<782, 256, 0, stream>>>(scratch, cursor, bstart, asc1, adc1, off, combo);
    agg1_kernel<<<(N_NODES + 3) / 4, 256, 0, stream>>>((const __half*)h1h, combo, b1, off, h1b);
    gemm2_mfma<<<391, 256, 0, stream>>>(h1b, w2h, as2, ad2, h2h, asc2, adc2);
    agg2_kernel<<<(N_NODES + 3) / 4, 256, 0, stream>>>(h2h, combo, asc2, adc2, b2, off, out);
}

// Round 11
// 160.173 us; speedup vs baseline: 1.4501x; 1.0408x over previous
//
#include <hip/hip_runtime.h>
#include <hip/hip_fp16.h>

#define N_NODES 50000
#define E_EDGES 800000
#define ET (E_EDGES + N_NODES)
#define NBKT 1024          // padded bucket count (782 used)
#define BCAP 2048          // scratch capacity per bucket
#define K1_BLOCKS 256
#define K1_EPB 3328        // 256*3328 = 851,968 >= ET

typedef _Float16 h8 __attribute__((ext_vector_type(8)));
typedef float f32x16 __attribute__((ext_vector_type(16)));

__device__ __forceinline__ float lrelu(float v) { return v > 0.f ? v : 0.2f * v; }

// ---------- K1 (fused): blocks [0,256) = coarse partition; blocks [256,285) = weight prep ----------
__global__ __launch_bounds__(256) void partprep_kernel(const int* __restrict__ ei,
                                                       const float* __restrict__ W1,
                                                       const float* __restrict__ W2,
                                                       const float* __restrict__ as1,
                                                       const float* __restrict__ ad1,
                                                       _Float16* __restrict__ w1h,
                                                       _Float16* __restrict__ w2h,
                                                       int* __restrict__ cursor,
                                                       int2* __restrict__ scratch) {
    int tid = threadIdx.x;
    if (blockIdx.x >= K1_BLOCKS) {
        int i = (blockIdx.x - K1_BLOCKS) * 256 + tid;
        if (i < 4096) {
            int j = i * 8;
#pragma unroll
            for (int t = 0; t < 8; t++) w1h[j + t] = (_Float16)W1[j + t];
        } else if (i < 4608) {
            int j = (i - 4096) * 8;
#pragma unroll
            for (int t = 0; t < 8; t++) w2h[j + t] = (_Float16)W2[j + t];
        } else if (i < 5376) {
            int j = (i - 4608) * 8;
#pragma unroll
            for (int t = 0; t < 8; t++) w1h[136 * 256 + j + t] = (_Float16)0.f;
        } else if (i < 7424) {
            int a = i - 5376;  // 0..2047
            int h = a >> 8, k = a & 255;
            const float* av = (h < 4 ? as1 : ad1) + (h & 3) * 32;
            const float* wb = W1 + (size_t)(h & 3) * 32 * 256 + k;
            float s = 0.f;
#pragma unroll
            for (int c = 0; c < 32; c++) s += av[c] * wb[(size_t)c * 256];
            w1h[(size_t)(128 + h) * 256 + k] = (_Float16)s;
        }
        return;
    }
    __shared__ int hcnt[NBKT];
    __shared__ int hbase[NBKT];
#pragma unroll
    for (int u = 0; u < NBKT / 256; u++) hcnt[u * 256 + tid] = 0;
    __syncthreads();
    int e0 = blockIdx.x * K1_EPB;
    for (int k = tid; k < K1_EPB; k += 256) {
        int i = e0 + k;
        if (i >= ET) break;
        int d = (i < E_EDGES) ? ei[E_EDGES + i] : (i - E_EDGES);
        atomicAdd(&hcnt[d >> 6], 1);
    }
    __syncthreads();
#pragma unroll
    for (int u = 0; u < NBKT / 256; u++) {
        int b = u * 256 + tid;
        int c = hcnt[b];
        hbase[b] = (c > 0) ? atomicAdd(&cursor[b], c) : 0;
        hcnt[b] = 0;
    }
    __syncthreads();
    for (int k = tid; k < K1_EPB; k += 256) {
        int i = e0 + k;
        if (i >= ET) break;
        int s, d;
        if (i < E_EDGES) { s = ei[i]; d = ei[E_EDGES + i]; }
        else { s = i - E_EDGES; d = s; }
        int b = d >> 6;
        int pos = hbase[b] + atomicAdd(&hcnt[b], 1);
        scratch[(size_t)b * BCAP + pos] = make_int2(s, d);
    }
}

// ---------- GEMM1 (MFMA): h1h[N,128] = cvt(x) @ w1h[0:128]^T ; cols 128..135 -> asc1/adc1 ----------
__global__ __launch_bounds__(256) void gemm1_mfma(const float* __restrict__ x,
                                                  const _Float16* __restrict__ w1h,
                                                  _Float16* __restrict__ h1h,
                                                  float* __restrict__ asc1,
                                                  float* __restrict__ adc1) {
    int wid = threadIdx.x >> 6, lane = threadIdx.x & 63;
    int rbase = blockIdx.x * 128 + wid * 32;
    if (rbase >= N_NODES) return;
    int l31 = lane & 31, l5 = lane >> 5;
    int ar = rbase + l31;
    if (ar > N_NODES - 1) ar = N_NODES - 1;
    const float* ap = x + (size_t)ar * 256 + l5 * 8;
    const _Float16* bp = w1h + (size_t)l31 * 256 + l5 * 8;
    f32x16 acc0 = {}, acc1 = {}, acc2 = {}, acc3 = {}, acc4 = {};
#pragma unroll 4
    for (int ks = 0; ks < 16; ks++) {
        float4 xa = *(const float4*)(ap + ks * 16);
        float4 xb = *(const float4*)(ap + ks * 16 + 4);
        h8 av;
        av[0] = (_Float16)xa.x; av[1] = (_Float16)xa.y;
        av[2] = (_Float16)xa.z; av[3] = (_Float16)xa.w;
        av[4] = (_Float16)xb.x; av[5] = (_Float16)xb.y;
        av[6] = (_Float16)xb.z; av[7] = (_Float16)xb.w;
        h8 b0 = *(const h8*)(bp + ks * 16);
        h8 b1 = *(const h8*)(bp + 32 * 256 + ks * 16);
        h8 b2 = *(const h8*)(bp + 64 * 256 + ks * 16);
        h8 b3 = *(const h8*)(bp + 96 * 256 + ks * 16);
        h8 b4 = *(const h8*)(bp + 128 * 256 + ks * 16);
        acc0 = __builtin_amdgcn_mfma_f32_32x32x16_f16(av, b0, acc0, 0, 0, 0);
        acc1 = __builtin_amdgcn_mfma_f32_32x32x16_f16(av, b1, acc1, 0, 0, 0);
        acc2 = __builtin_amdgcn_mfma_f32_32x32x16_f16(av, b2, acc2, 0, 0, 0);
        acc3 = __builtin_amdgcn_mfma_f32_32x32x16_f16(av, b3, acc3, 0, 0, 0);
        acc4 = __builtin_amdgcn_mfma_f32_32x32x16_f16(av, b4, acc4, 0, 0, 0);
    }
#pragma unroll
    for (int j = 0; j < 16; j++) {
        int row = rbase + (j & 3) + 8 * (j >> 2) + 4 * l5;
        if (row < N_NODES) {
            h1h[(size_t)row * 128 + 0  + l31] = (_Float16)acc0[j];
            h1h[(size_t)row * 128 + 32 + l31] = (_Float16)acc1[j];
            h1h[(size_t)row * 128 + 64 + l31] = (_Float16)acc2[j];
            h1h[(size_t)row * 128 + 96 + l31] = (_Float16)acc3[j];
            float v4 = acc4[j];
            if (l31 < 4) asc1[(size_t)row * 4 + l31] = v4;
            else if (l31 < 8) adc1[(size_t)row * 4 + (l31 - 4)] = v4;
        }
    }
}

// ---------- K3: fine sort within bucket (64 nodes) + self-scan of bucket bases; write off/combo/srcs ----------
__global__ __launch_bounds__(256) void fine_kernel(const int2* __restrict__ scratch,
                                                   const int* __restrict__ cursor,
                                                   const float* __restrict__ asc1,
                                                   const float* __restrict__ adc1,
                                                   int* __restrict__ off,
                                                   int4* __restrict__ combo,
                                                   int* __restrict__ srcs) {
    __shared__ int2 rec[BCAP];
    __shared__ int fh[64];
    __shared__ int fcur[64];
    __shared__ int red[256];
    int b = blockIdx.x;
    int tid = threadIdx.x;
    int cnt = cursor[b];
    // self-scan: gbase = sum cursor[0..b)
    int part = 0;
    for (int i = tid; i < b; i += 256) part += cursor[i];
    red[tid] = part;
    if (tid < 64) fh[tid] = 0;
    __syncthreads();
    for (int s = 128; s >= 1; s >>= 1) {
        if (tid < s) red[tid] += red[tid + s];
        __syncthreads();
    }
    int gbase = red[0];
    for (int k = tid; k < cnt; k += 256) {
        int2 r = scratch[(size_t)b * BCAP + k];
        rec[k] = r;
        atomicAdd(&fh[r.y & 63], 1);
    }
    __syncthreads();
    if (tid < 64) {
        int v = fh[tid];
        int incl = v;
#pragma unroll
        for (int d = 1; d < 64; d <<= 1) {
            int u = __shfl_up(incl, d);
            if (tid >= d) incl += u;
        }
        int excl = incl - v;
        fcur[tid] = excl;
        int n = b * 64 + tid;
        if (n < N_NODES) off[n] = gbase + excl;
    }
    if (b == 781 && tid == 0) off[N_NODES] = ET;
    __syncthreads();
    for (int k = tid; k < cnt; k += 256) {
        int2 r = rec[k];
        int pos = gbase + atomicAdd(&fcur[r.y & 63], 1);
        float4 av = *(const float4*)(asc1 + (size_t)r.x * 4);
        float4 dv = *(const float4*)(adc1 + (size_t)r.y * 4);
        __half2 p01 = __floats2half2_rn(__expf(lrelu(av.x + dv.x)), __expf(lrelu(av.y + dv.y)));
        __half2 p23 = __floats2half2_rn(__expf(lrelu(av.z + dv.z)), __expf(lrelu(av.w + dv.w)));
        int4 o;
        o.x = r.x;
        o.y = *(int*)&p01;
        o.z = *(int*)&p23;
        o.w = 0;
        combo[pos] = o;
        srcs[pos] = r.x;
    }
}

// ---------- Layer-1 aggregation: wave per node, 8 gathers in flight (r6 form) ----------
__global__ __launch_bounds__(256) void agg1_kernel(const __half* __restrict__ h1h,
                                                   const int4* __restrict__ combo,
                                                   const float* __restrict__ b1,
                                                   const int* __restrict__ off,
                                                   __half* __restrict__ h1b) {
    int wid = threadIdx.x >> 6, lane = threadIdx.x & 63;
    int node = blockIdx.x * 4 + wid;
    if (node >= N_NODES) return;
    int hh = lane >> 4;
    const __half2* h1h2 = (const __half2*)h1h;
    int s0 = off[node], s1 = off[node + 1];
    float den = 0.f, a0 = 0.f, a1 = 0.f;
    int j = s0;
    for (; j + 8 <= s1; j += 8) {
        int4 c[8];
#pragma unroll
        for (int u = 0; u < 8; u++) c[u] = combo[j + u];
        __half2 hv[8];
#pragma unroll
        for (int u = 0; u < 8; u++) hv[u] = h1h2[(size_t)c[u].x * 64 + lane];
#pragma unroll
        for (int u = 0; u < 8; u++) {
            union { int u32; __half2 h; } v;
            v.u32 = (hh & 2) ? c[u].z : c[u].y;
            float p = __half2float((hh & 1) ? v.h.y : v.h.x);
            float2 f = __half22float2(hv[u]);
            den += p;
            a0 += p * f.x;
            a1 += p * f.y;
        }
    }
    for (; j + 4 <= s1; j += 4) {
        int4 c[4];
#pragma unroll
        for (int u = 0; u < 4; u++) c[u] = combo[j + u];
        __half2 hv[4];
#pragma unroll
        for (int u = 0; u < 4; u++) hv[u] = h1h2[(size_t)c[u].x * 64 + lane];
#pragma unroll
        for (int u = 0; u < 4; u++) {
            union { int u32; __half2 h; } v;
            v.u32 = (hh & 2) ? c[u].z : c[u].y;
            float p = __half2float((hh & 1) ? v.h.y : v.h.x);
            float2 f = __half22float2(hv[u]);
            den += p;
            a0 += p * f.x;
            a1 += p * f.y;
        }
    }
    for (; j < s1; j++) {
        int4 c = combo[j];
        union { int u32; __half2 h; } v;
        v.u32 = (hh & 2) ? c.z : c.y;
        float p = __half2float((hh & 1) ? v.h.y : v.h.x);
        float2 f = __half22float2(h1h2[(size_t)c.x * 64 + lane]);
        den += p;
        a0 += p * f.x;
        a1 += p * f.y;
    }
    float inv = 1.f / (den + 1e-16f);
    float o0 = fmaxf(a0 * inv + b1[2 * lane], 0.f);
    float o1 = fmaxf(a1 * inv + b1[2 * lane + 1], 0.f);
    ((__half2*)h1b)[(size_t)node * 64 + lane] = __floats2half2_rn(o0, o1);
}

// ---------- GEMM2 (MFMA): h2h[N,32] = h1b @ w2h^T ; epilogue asc2/adc2 ----------
__global__ __launch_bounds__(256) void gemm2_mfma(const __half* __restrict__ h1b,
                                                  const _Float16* __restrict__ w2h,
                                                  const float* __restrict__ as2,
                                                  const float* __restrict__ ad2,
                                                  __half* __restrict__ h2h,
                                                  float* __restrict__ asc2,
                                                  float* __restrict__ adc2) {
    int wid = threadIdx.x >> 6, lane = threadIdx.x & 63;
    int rbase = blockIdx.x * 128 + wid * 32;
    if (rbase >= N_NODES) return;
    int l31 = lane & 31, l5 = lane >> 5;
    int ar = rbase + l31;
    if (ar > N_NODES - 1) ar = N_NODES - 1;
    const _Float16* ap = (const _Float16*)h1b + (size_t)ar * 128 + l5 * 8;
    const _Float16* bp = w2h + (size_t)l31 * 128 + l5 * 8;
    f32x16 acc = {};
#pragma unroll
    for (int ks = 0; ks < 8; ks++) {
        h8 av = *(const h8*)(ap + ks * 16);
        h8 bv = *(const h8*)(bp + ks * 16);
        acc = __builtin_amdgcn_mfma_f32_32x32x16_f16(av, bv, acc, 0, 0, 0);
    }
    float asw = as2[l31], adw = ad2[l31];
#pragma unroll
    for (int j = 0; j < 16; j++) {
        int row = rbase + (j & 3) + 8 * (j >> 2) + 4 * l5;
        float v = acc[j];
        float sv = v * asw, dv = v * adw;
#pragma unroll
        for (int m = 1; m <= 16; m <<= 1) {
            sv += __shfl_xor(sv, m);
            dv += __shfl_xor(dv, m);
        }
        if (row < N_NODES) {
            h2h[(size_t)row * 32 + l31] = __float2half(v);
            if (l31 == 0) { asc2[row] = sv; adc2[row] = dv; }
        }
    }
}

// ---------- Layer-2 aggregation + log_softmax (p2 on the fly, compact srcs) ----------
__global__ __launch_bounds__(256) void agg2_kernel(const __half* __restrict__ h2h,
                                                   const int* __restrict__ srcs,
                                                   const float* __restrict__ asc2,
                                                   const float* __restrict__ adc2,
                                                   const float* __restrict__ b2,
                                                   const int* __restrict__ off,
                                                   float* __restrict__ out) {
    int wid = threadIdx.x >> 6, lane = threadIdx.x & 63;
    int node = blockIdx.x * 4 + wid;
    if (node >= N_NODES) return;
    int g = lane >> 4;
    int li = lane & 15;
    const __half2* h2h2 = (const __half2*)h2h;
    float adv = adc2[node];
    int s0 = off[node], s1 = off[node + 1];
    float den = 0.f, a0 = 0.f, a1 = 0.f;
    int j = s0 + g;
    for (; j + 16 <= s1; j += 16) {
        int s[4];
#pragma unroll
        for (int u = 0; u < 4; u++) s[u] = srcs[j + 4 * u];
        float av[4];
#pragma unroll
        for (int u = 0; u < 4; u++) av[u] = asc2[s[u]];
        __half2 hv[4];
#pragma unroll
        for (int u = 0; u < 4; u++) hv[u] = h2h2[(size_t)s[u] * 16 + li];
#pragma unroll
        for (int u = 0; u < 4; u++) {
            float p = __expf(lrelu(av[u] + adv));
            float2 f = __half22float2(hv[u]);
            den += p;
            a0 += p * f.x;
            a1 += p * f.y;
        }
    }
    for (; j < s1; j += 4) {
        int s = srcs[j];
        float p = __expf(lrelu(asc2[s] + adv));
        float2 f = __half22float2(h2h2[(size_t)s * 16 + li]);
        den += p;
        a0 += p * f.x;
        a1 += p * f.y;
    }
    den += __shfl_xor(den, 16); den += __shfl_xor(den, 32);
    a0 += __shfl_xor(a0, 16);  a0 += __shfl_xor(a0, 32);
    a1 += __shfl_xor(a1, 16);  a1 += __shfl_xor(a1, 32);
    float inv = 1.f / (den + 1e-16f);
    float v0 = a0 * inv + b2[2 * li];
    float v1 = a1 * inv + b2[2 * li + 1];
    float mx = fmaxf(v0, v1);
#pragma unroll
    for (int msk = 8; msk >= 1; msk >>= 1) mx = fmaxf(mx, __shfl_xor(mx, msk));
    float se = __expf(v0 - mx) + __expf(v1 - mx);
#pragma unroll
    for (int msk = 8; msk >= 1; msk >>= 1) se += __shfl_xor(se, msk);
    float lse = mx + __logf(se);
    if (lane < 16) {
        ((float2*)out)[(size_t)node * 16 + li] = make_float2(v0 - lse, v1 - lse);
    }
}

extern "C" void kernel_launch(void* const* d_in, const int* in_sizes, int n_in,
                              void* d_out, int out_size, void* d_ws, size_t ws_size,
                              hipStream_t stream) {
    const float* x   = (const float*)d_in[0];
    const int* ei    = (const int*)d_in[1];
    const float* W1  = (const float*)d_in[2];
    const float* as1 = (const float*)d_in[3];
    const float* ad1 = (const float*)d_in[4];
    const float* b1  = (const float*)d_in[5];
    const float* W2  = (const float*)d_in[6];
    const float* as2 = (const float*)d_in[7];
    const float* ad2 = (const float*)d_in[8];
    const float* b2  = (const float*)d_in[9];
    float* out = (float*)d_out;

    char* base = (char*)d_ws;
    int4* combo   = (int4*)base;                        // 13,600,000
    int2* scratch = (int2*)(base + 13600000);           // 16,777,216
    _Float16* w1h = (_Float16*)(base + 30377216);       // 81,920
    _Float16* w2h = (_Float16*)(base + 30459136);       // 8,192
    _Float16* h1h = (_Float16*)(base + 30467328);       // 12,800,000
    __half* h1b   = (__half*)(base + 43267328);         // 12,800,000
    __half* h2h   = (__half*)(base + 56067328);         //  3,200,000
    float* asc1   = (float*)(base + 59267328);          //    800,000
    float* adc1   = (float*)(base + 60067328);          //    800,000
    float* asc2   = (float*)(base + 60867328);          //    200,000
    float* adc2   = (float*)(base + 61067328);          //    200,000
    int* off      = (int*)(base + 61267328);            //    200,004
    int* cursor   = (int*)(base + 61467332);            //      4,096
    int* srcs     = (int*)(base + 61471428);            //  3,400,000

    hipMemsetAsync(cursor, 0, NBKT * sizeof(int), stream);

    partprep_kernel<<<K1_BLOCKS + 29, 256, 0, stream>>>(ei, W1, W2, as1, ad1, w1h, w2h, cursor, scratch);
    gemm1_mfma<<<391, 256, 0, stream>>>(x, w1h, h1h, asc1, adc1);
    fine_kernel<<<782, 256, 0, stream>>>(scratch, cursor, asc1, adc1, off, combo, srcs);
    agg1_kernel<<<(N_NODES + 3) / 4, 256, 0, stream>>>((const __half*)h1h, combo, b1, off, h1b);
    gemm2_mfma<<<391, 256, 0, stream>>>(h1b, w2h, as2, ad2, h2h, asc2, adc2);
    agg2_kernel<<<(N_NODES + 3) / 4, 256, 0, stream>>>(h2h, srcs, asc2, adc2, b2, off, out);
}

// Round 12
// 139.260 us; speedup vs baseline: 1.6678x; 1.1502x over previous
//
#include <hip/hip_runtime.h>
#include <hip/hip_fp16.h>

#define N_NODES 50000
#define E_EDGES 800000
#define ET (E_EDGES + N_NODES)
#define NBKT 1024          // padded bucket count (782 used)
#define BCAP 2048          // scratch capacity per bucket
#define G1_BLOCKS 391
#define P_BLOCKS 250
#define P_EPB 3200         // 250*3200 = 800,000 edges exactly

typedef _Float16 h8 __attribute__((ext_vector_type(8)));
typedef float f32x16 __attribute__((ext_vector_type(16)));

__device__ __forceinline__ float lrelu(float v) { return v > 0.f ? v : 0.2f * v; }

// ---------- prep: W1/W2 fp16 + Aw rows + cursor zero ----------
__global__ __launch_bounds__(256) void prep_kernel(const float* __restrict__ W1,
                                                   const float* __restrict__ W2,
                                                   const float* __restrict__ as1,
                                                   const float* __restrict__ ad1,
                                                   _Float16* __restrict__ w1h,
                                                   _Float16* __restrict__ w2h,
                                                   int* __restrict__ cursor) {
    int i = blockIdx.x * 256 + threadIdx.x;
    if (i < 1024) cursor[i] = 0;
    if (i < 4096) {
        int j = i * 8;
#pragma unroll
        for (int t = 0; t < 8; t++) w1h[j + t] = (_Float16)W1[j + t];
    } else if (i < 4608) {
        int j = (i - 4096) * 8;
#pragma unroll
        for (int t = 0; t < 8; t++) w2h[j + t] = (_Float16)W2[j + t];
    } else if (i < 5376) {
        int j = (i - 4608) * 8;
#pragma unroll
        for (int t = 0; t < 8; t++) w1h[136 * 256 + j + t] = (_Float16)0.f;
    } else if (i < 7424) {
        int a = i - 5376;  // 0..2047
        int h = a >> 8, k = a & 255;
        const float* av = (h < 4 ? as1 : ad1) + (h & 3) * 32;
        const float* wb = W1 + (size_t)(h & 3) * 32 * 256 + k;
        float s = 0.f;
#pragma unroll
        for (int c = 0; c < 32; c++) s += av[c] * wb[(size_t)c * 256];
        w1h[(size_t)(128 + h) * 256 + k] = (_Float16)s;
    }
}

// ---------- fused: blocks [0,391) = GEMM1 (MFMA); blocks [391,641) = coarse edge partition ----------
__global__ __launch_bounds__(256) void gp_kernel(const float* __restrict__ x,
                                                 const int* __restrict__ ei,
                                                 const _Float16* __restrict__ w1h,
                                                 _Float16* __restrict__ h1h,
                                                 float* __restrict__ asc1,
                                                 float* __restrict__ adc1,
                                                 int* __restrict__ cursor,
                                                 int2* __restrict__ scratch) {
    __shared__ int hcnt[NBKT];
    __shared__ int hbase[NBKT];
    int tid = threadIdx.x;
    if (blockIdx.x >= G1_BLOCKS) {
        // ----- edge partition by dst>>6, int4 loads, LDS histogram, 1 reserve atomic per block-bucket -----
        int b = blockIdx.x - G1_BLOCKS;
#pragma unroll
        for (int u = 0; u < NBKT / 256; u++) hcnt[u * 256 + tid] = 0;
        __syncthreads();
        int e0 = b * P_EPB;
        const int4* s4 = (const int4*)(ei + e0);
        const int4* d4 = (const int4*)(ei + E_EDGES + e0);
        for (int q = tid; q < P_EPB / 4; q += 256) {
            int4 d = d4[q];
            atomicAdd(&hcnt[d.x >> 6], 1);
            atomicAdd(&hcnt[d.y >> 6], 1);
            atomicAdd(&hcnt[d.z >> 6], 1);
            atomicAdd(&hcnt[d.w >> 6], 1);
        }
        __syncthreads();
#pragma unroll
        for (int u = 0; u < NBKT / 256; u++) {
            int bb = u * 256 + tid;
            int c = hcnt[bb];
            hbase[bb] = (c > 0) ? atomicAdd(&cursor[bb], c) : 0;
            hcnt[bb] = 0;
        }
        __syncthreads();
        for (int q = tid; q < P_EPB / 4; q += 256) {
            int4 s = s4[q];
            int4 d = d4[q];
            int bk, pos;
            bk = d.x >> 6; pos = hbase[bk] + atomicAdd(&hcnt[bk], 1);
            scratch[(size_t)bk * BCAP + pos] = make_int2(s.x, d.x);
            bk = d.y >> 6; pos = hbase[bk] + atomicAdd(&hcnt[bk], 1);
            scratch[(size_t)bk * BCAP + pos] = make_int2(s.y, d.y);
            bk = d.z >> 6; pos = hbase[bk] + atomicAdd(&hcnt[bk], 1);
            scratch[(size_t)bk * BCAP + pos] = make_int2(s.z, d.z);
            bk = d.w >> 6; pos = hbase[bk] + atomicAdd(&hcnt[bk], 1);
            scratch[(size_t)bk * BCAP + pos] = make_int2(s.w, d.w);
        }
        return;
    }
    // ----- GEMM1 -----
    int wid = tid >> 6, lane = tid & 63;
    int rbase = blockIdx.x * 128 + wid * 32;
    if (rbase >= N_NODES) return;
    int l31 = lane & 31, l5 = lane >> 5;
    int ar = rbase + l31;
    if (ar > N_NODES - 1) ar = N_NODES - 1;
    const float* ap = x + (size_t)ar * 256 + l5 * 8;
    const _Float16* bp = w1h + (size_t)l31 * 256 + l5 * 8;
    f32x16 acc0 = {}, acc1 = {}, acc2 = {}, acc3 = {}, acc4 = {};
#pragma unroll 4
    for (int ks = 0; ks < 16; ks++) {
        float4 xa = *(const float4*)(ap + ks * 16);
        float4 xb = *(const float4*)(ap + ks * 16 + 4);
        h8 av;
        av[0] = (_Float16)xa.x; av[1] = (_Float16)xa.y;
        av[2] = (_Float16)xa.z; av[3] = (_Float16)xa.w;
        av[4] = (_Float16)xb.x; av[5] = (_Float16)xb.y;
        av[6] = (_Float16)xb.z; av[7] = (_Float16)xb.w;
        h8 b0 = *(const h8*)(bp + ks * 16);
        h8 b1 = *(const h8*)(bp + 32 * 256 + ks * 16);
        h8 b2 = *(const h8*)(bp + 64 * 256 + ks * 16);
        h8 b3 = *(const h8*)(bp + 96 * 256 + ks * 16);
        h8 b4 = *(const h8*)(bp + 128 * 256 + ks * 16);
        acc0 = __builtin_amdgcn_mfma_f32_32x32x16_f16(av, b0, acc0, 0, 0, 0);
        acc1 = __builtin_amdgcn_mfma_f32_32x32x16_f16(av, b1, acc1, 0, 0, 0);
        acc2 = __builtin_amdgcn_mfma_f32_32x32x16_f16(av, b2, acc2, 0, 0, 0);
        acc3 = __builtin_amdgcn_mfma_f32_32x32x16_f16(av, b3, acc3, 0, 0, 0);
        acc4 = __builtin_amdgcn_mfma_f32_32x32x16_f16(av, b4, acc4, 0, 0, 0);
    }
#pragma unroll
    for (int j = 0; j < 16; j++) {
        int row = rbase + (j & 3) + 8 * (j >> 2) + 4 * l5;
        if (row < N_NODES) {
            h1h[(size_t)row * 128 + 0  + l31] = (_Float16)acc0[j];
            h1h[(size_t)row * 128 + 32 + l31] = (_Float16)acc1[j];
            h1h[(size_t)row * 128 + 64 + l31] = (_Float16)acc2[j];
            h1h[(size_t)row * 128 + 96 + l31] = (_Float16)acc3[j];
            float v4 = acc4[j];
            if (l31 < 4) asc1[(size_t)row * 4 + l31] = v4;
            else if (l31 < 8) adc1[(size_t)row * 4 + (l31 - 4)] = v4;
        }
    }
}

// ---------- K3: fine sort within bucket (64 nodes) + self-scan; self-loops emitted directly ----------
__global__ __launch_bounds__(256) void fine_kernel(const int2* __restrict__ scratch,
                                                   const int* __restrict__ cursor,
                                                   const float* __restrict__ asc1,
                                                   const float* __restrict__ adc1,
                                                   int* __restrict__ off,
                                                   int4* __restrict__ combo,
                                                   int* __restrict__ srcs) {
    __shared__ int2 rec[BCAP];
    __shared__ int fh[64];
    __shared__ int fcur[64];
    __shared__ int red[256];
    int b = blockIdx.x;
    int tid = threadIdx.x;
    int cnt = cursor[b];
    // self-scan: gbase = sum cursor[0..b) + b*64 self-loops
    int part = 0;
    for (int i = tid; i < b; i += 256) part += cursor[i];
    red[tid] = part;
    if (tid < 64) fh[tid] = (b * 64 + tid < N_NODES) ? 1 : 0;  // self-loop slot
    __syncthreads();
    for (int s = 128; s >= 1; s >>= 1) {
        if (tid < s) red[tid] += red[tid + s];
        __syncthreads();
    }
    int gbase = red[0] + b * 64;
    for (int k = tid; k < cnt; k += 256) {
        int2 r = scratch[(size_t)b * BCAP + k];
        rec[k] = r;
        atomicAdd(&fh[r.y & 63], 1);
    }
    __syncthreads();
    if (tid < 64) {
        int v = fh[tid];
        int incl = v;
#pragma unroll
        for (int d = 1; d < 64; d <<= 1) {
            int u = __shfl_up(incl, d);
            if (tid >= d) incl += u;
        }
        int excl = incl - v;
        fcur[tid] = excl;
        int n = b * 64 + tid;
        if (n < N_NODES) off[n] = gbase + excl;
    }
    if (b == 781 && tid == 0) off[N_NODES] = ET;
    __syncthreads();
    // self-loop record for node n = b*64 + tid
    if (tid < 64) {
        int n = b * 64 + tid;
        if (n < N_NODES) {
            int pos = gbase + atomicAdd(&fcur[tid], 1);
            float4 av = *(const float4*)(asc1 + (size_t)n * 4);
            float4 dv = *(const float4*)(adc1 + (size_t)n * 4);
            __half2 p01 = __floats2half2_rn(__expf(lrelu(av.x + dv.x)), __expf(lrelu(av.y + dv.y)));
            __half2 p23 = __floats2half2_rn(__expf(lrelu(av.z + dv.z)), __expf(lrelu(av.w + dv.w)));
            int4 o;
            o.x = n;
            o.y = *(int*)&p01;
            o.z = *(int*)&p23;
            o.w = 0;
            combo[pos] = o;
            srcs[pos] = n;
        }
    }
    for (int k = tid; k < cnt; k += 256) {
        int2 r = rec[k];
        int pos = gbase + atomicAdd(&fcur[r.y & 63], 1);
        float4 av = *(const float4*)(asc1 + (size_t)r.x * 4);
        float4 dv = *(const float4*)(adc1 + (size_t)r.y * 4);
        __half2 p01 = __floats2half2_rn(__expf(lrelu(av.x + dv.x)), __expf(lrelu(av.y + dv.y)));
        __half2 p23 = __floats2half2_rn(__expf(lrelu(av.z + dv.z)), __expf(lrelu(av.w + dv.w)));
        int4 o;
        o.x = r.x;
        o.y = *(int*)&p01;
        o.z = *(int*)&p23;
        o.w = 0;
        combo[pos] = o;
        srcs[pos] = r.x;
    }
}

// ---------- Layer-1 aggregation: wave per node, 8 gathers in flight (r6 form, unchanged) ----------
__global__ __launch_bounds__(256) void agg1_kernel(const __half* __restrict__ h1h,
                                                   const int4* __restrict__ combo,
                                                   const float* __restrict__ b1,
                                                   const int* __restrict__ off,
                                                   __half* __restrict__ h1b) {
    int wid = threadIdx.x >> 6, lane = threadIdx.x & 63;
    int node = blockIdx.x * 4 + wid;
    if (node >= N_NODES) return;
    int hh = lane >> 4;
    const __half2* h1h2 = (const __half2*)h1h;
    int s0 = off[node], s1 = off[node + 1];
    float den = 0.f, a0 = 0.f, a1 = 0.f;
    int j = s0;
    for (; j + 8 <= s1; j += 8) {
        int4 c[8];
#pragma unroll
        for (int u = 0; u < 8; u++) c[u] = combo[j + u];
        __half2 hv[8];
#pragma unroll
        for (int u = 0; u < 8; u++) hv[u] = h1h2[(size_t)c[u].x * 64 + lane];
#pragma unroll
        for (int u = 0; u < 8; u++) {
            union { int u32; __half2 h; } v;
            v.u32 = (hh & 2) ? c[u].z : c[u].y;
            float p = __half2float((hh & 1) ? v.h.y : v.h.x);
            float2 f = __half22float2(hv[u]);
            den += p;
            a0 += p * f.x;
            a1 += p * f.y;
        }
    }
    for (; j + 4 <= s1; j += 4) {
        int4 c[4];
#pragma unroll
        for (int u = 0; u < 4; u++) c[u] = combo[j + u];
        __half2 hv[4];
#pragma unroll
        for (int u = 0; u < 4; u++) hv[u] = h1h2[(size_t)c[u].x * 64 + lane];
#pragma unroll
        for (int u = 0; u < 4; u++) {
            union { int u32; __half2 h; } v;
            v.u32 = (hh & 2) ? c[u].z : c[u].y;
            float p = __half2float((hh & 1) ? v.h.y : v.h.x);
            float2 f = __half22float2(hv[u]);
            den += p;
            a0 += p * f.x;
            a1 += p * f.y;
        }
    }
    for (; j < s1; j++) {
        int4 c = combo[j];
        union { int u32; __half2 h; } v;
        v.u32 = (hh & 2) ? c.z : c.y;
        float p = __half2float((hh & 1) ? v.h.y : v.h.x);
        float2 f = __half22float2(h1h2[(size_t)c.x * 64 + lane]);
        den += p;
        a0 += p * f.x;
        a1 += p * f.y;
    }
    float inv = 1.f / (den + 1e-16f);
    float o0 = fmaxf(a0 * inv + b1[2 * lane], 0.f);
    float o1 = fmaxf(a1 * inv + b1[2 * lane + 1], 0.f);
    ((__half2*)h1b)[(size_t)node * 64 + lane] = __floats2half2_rn(o0, o1);
}

// ---------- GEMM2 (MFMA): h2h[N,32] = h1b @ w2h^T ; epilogue asc2/adc2 ----------
__global__ __launch_bounds__(256) void gemm2_mfma(const __half* __restrict__ h1b,
                                                  const _Float16* __restrict__ w2h,
                                                  const float* __restrict__ as2,
                                                  const float* __restrict__ ad2,
                                                  __half* __restrict__ h2h,
                                                  float* __restrict__ asc2,
                                                  float* __restrict__ adc2) {
    int wid = threadIdx.x >> 6, lane = threadIdx.x & 63;
    int rbase = blockIdx.x * 128 + wid * 32;
    if (rbase >= N_NODES) return;
    int l31 = lane & 31, l5 = lane >> 5;
    int ar = rbase + l31;
    if (ar > N_NODES - 1) ar = N_NODES - 1;
    const _Float16* ap = (const _Float16*)h1b + (size_t)ar * 128 + l5 * 8;
    const _Float16* bp = w2h + (size_t)l31 * 128 + l5 * 8;
    f32x16 acc = {};
#pragma unroll
    for (int ks = 0; ks < 8; ks++) {
        h8 av = *(const h8*)(ap + ks * 16);
        h8 bv = *(const h8*)(bp + ks * 16);
        acc = __builtin_amdgcn_mfma_f32_32x32x16_f16(av, bv, acc, 0, 0, 0);
    }
    float asw = as2[l31], adw = ad2[l31];
#pragma unroll
    for (int j = 0; j < 16; j++) {
        int row = rbase + (j & 3) + 8 * (j >> 2) + 4 * l5;
        float v = acc[j];
        float sv = v * asw, dv = v * adw;
#pragma unroll
        for (int m = 1; m <= 16; m <<= 1) {
            sv += __shfl_xor(sv, m);
            dv += __shfl_xor(dv, m);
        }
        if (row < N_NODES) {
            h2h[(size_t)row * 32 + l31] = __float2half(v);
            if (l31 == 0) { asc2[row] = sv; adc2[row] = dv; }
        }
    }
}

// ---------- Layer-2 aggregation + log_softmax (p2 on the fly, compact srcs) ----------
__global__ __launch_bounds__(256) void agg2_kernel(const __half* __restrict__ h2h,
                                                   const int* __restrict__ srcs,
                                                   const float* __restrict__ asc2,
                                                   const float* __restrict__ adc2,
                                                   const float* __restrict__ b2,
                                                   const int* __restrict__ off,
                                                   float* __restrict__ out) {
    int wid = threadIdx.x >> 6, lane = threadIdx.x & 63;
    int node = blockIdx.x * 4 + wid;
    if (node >= N_NODES) return;
    int g = lane >> 4;
    int li = lane & 15;
    const __half2* h2h2 = (const __half2*)h2h;
    float adv = adc2[node];
    int s0 = off[node], s1 = off[node + 1];
    float den = 0.f, a0 = 0.f, a1 = 0.f;
    int j = s0 + g;
    for (; j + 16 <= s1; j += 16) {
        int s[4];
#pragma unroll
        for (int u = 0; u < 4; u++) s[u] = srcs[j + 4 * u];
        float av[4];
#pragma unroll
        for (int u = 0; u < 4; u++) av[u] = asc2[s[u]];
        __half2 hv[4];
#pragma unroll
        for (int u = 0; u < 4; u++) hv[u] = h2h2[(size_t)s[u] * 16 + li];
#pragma unroll
        for (int u = 0; u < 4; u++) {
            float p = __expf(lrelu(av[u] + adv));
            float2 f = __half22float2(hv[u]);
            den += p;
            a0 += p * f.x;
            a1 += p * f.y;
        }
    }
    for (; j < s1; j += 4) {
        int s = srcs[j];
        float p = __expf(lrelu(asc2[s] + adv));
        float2 f = __half22float2(h2h2[(size_t)s * 16 + li]);
        den += p;
        a0 += p * f.x;
        a1 += p * f.y;
    }
    den += __shfl_xor(den, 16); den += __shfl_xor(den, 32);
    a0 += __shfl_xor(a0, 16);  a0 += __shfl_xor(a0, 32);
    a1 += __shfl_xor(a1, 16);  a1 += __shfl_xor(a1, 32);
    float inv = 1.f / (den + 1e-16f);
    float v0 = a0 * inv + b2[2 * li];
    float v1 = a1 * inv + b2[2 * li + 1];
    float mx = fmaxf(v0, v1);
#pragma unroll
    for (int msk = 8; msk >= 1; msk >>= 1) mx = fmaxf(mx, __shfl_xor(mx, msk));
    float se = __expf(v0 - mx) + __expf(v1 - mx);
#pragma unroll
    for (int msk = 8; msk >= 1; msk >>= 1) se += __shfl_xor(se, msk);
    float lse = mx + __logf(se);
    if (lane < 16) {
        ((float2*)out)[(size_t)node * 16 + li] = make_float2(v0 - lse, v1 - lse);
    }
}

extern "C" void kernel_launch(void* const* d_in, const int* in_sizes, int n_in,
                              void* d_out, int out_size, void* d_ws, size_t ws_size,
                              hipStream_t stream) {
    const float* x   = (const float*)d_in[0];
    const int* ei    = (const int*)d_in[1];
    const float* W1  = (const float*)d_in[2];
    const float* as1 = (const float*)d_in[3];
    const float* ad1 = (const float*)d_in[4];
    const float* b1  = (const float*)d_in[5];
    const float* W2  = (const float*)d_in[6];
    const float* as2 = (const float*)d_in[7];
    const float* ad2 = (const float*)d_in[8];
    const float* b2  = (const float*)d_in[9];
    float* out = (float*)d_out;

    char* base = (char*)d_ws;
    int4* combo   = (int4*)base;                        // 13,600,000
    int2* scratch = (int2*)(base + 13600000);           // 16,777,216
    _Float16* w1h = (_Float16*)(base + 30377216);       // 81,920
    _Float16* w2h = (_Float16*)(base + 30459136);       // 8,192
    _Float16* h1h = (_Float16*)(base + 30467328);       // 12,800,000
    __half* h1b   = (__half*)(base + 43267328);         // 12,800,000
    __half* h2h   = (__half*)(base + 56067328);         //  3,200,000
    float* asc1   = (float*)(base + 59267328);          //    800,000
    float* adc1   = (float*)(base + 60067328);          //    800,000
    float* asc2   = (float*)(base + 60867328);          //    200,000
    float* adc2   = (float*)(base + 61067328);          //    200,000
    int* off      = (int*)(base + 61267328);            //    200,004
    int* cursor   = (int*)(base + 61467332);            //      4,096
    int* srcs     = (int*)(base + 61471428);            //  3,400,000

    prep_kernel<<<29, 256, 0, stream>>>(W1, W2, as1, ad1, w1h, w2h, cursor);
    gp_kernel<<<G1_BLOCKS + P_BLOCKS, 256, 0, stream>>>(x, ei, w1h, h1h, asc1, adc1, cursor, scratch);
    fine_kernel<<<782, 256, 0, stream>>>(scratch, cursor, asc1, adc1, off, combo, srcs);
    agg1_kernel<<<(N_NODES + 3) / 4, 256, 0, stream>>>((const __half*)h1h, combo, b1, off, h1b);
    gemm2_mfma<<<391, 256, 0, stream>>>(h1b, w2h, as2, ad2, h2h, asc2, adc2);
    agg2_kernel<<<(N_NODES + 3) / 4, 256, 0, stream>>>(h2h, srcs, asc2, adc2, b2, off, out);
}